// Round 1
// baseline (2993.374 us; speedup 1.0000x reference)
//
#include <hip/hip_runtime.h>
#include <math.h>

#define NN 50000
#define NE 500000
#define EEDG 550000          // NE + NN self loops
#define SDIM 128             // STRUCT
#define MDIM 768             // SEM
#define HIDD 128             // HID
#define NHEADS 4
#define INDIM 896            // STRUCT + SEM
#define H1D 512              // HEADS*HID

// ---------------- utility ----------------
__device__ __forceinline__ void atomicMaxF(float* addr, float val) {
    int* ia = (int*)addr;
    int old = __float_as_int(*addr);
    while (__int_as_float(old) < val) {
        int assumed = old;
        old = atomicCAS(ia, assumed, __float_as_int(val));
        if (old == assumed) break;
    }
}

__device__ __forceinline__ void edge_sd(const int* __restrict__ ei, int e, int& s, int& d) {
    if (e < NE) { s = ei[e]; d = ei[NE + e]; }
    else        { s = e - NE; d = e - NE; }
}

__global__ void fillk(float* __restrict__ p, float v, long count) {
    long i = (long)blockIdx.x * blockDim.x + threadIdx.x;
    long stride = (long)gridDim.x * blockDim.x;
    for (; i < count; i += stride) p[i] = v;
}

__global__ void rowinit(float* __restrict__ p, const float* __restrict__ bias, long total, int cmask) {
    long i = (long)blockIdx.x * blockDim.x + threadIdx.x;
    long stride = (long)gridDim.x * blockDim.x;
    for (; i < total; i += stride) p[i] = bias[i & cmask];
}

// ---------------- GEMM: C[M x Ncols] = A[M x K] @ B[K x Ncols] (+bias)(+=C) ----------------
// row-major. K % 16 == 0, Ncols % 64 == 0 required.
__global__ __launch_bounds__(256) void gemm_f32(
    const float* __restrict__ A, int lda,
    const float* __restrict__ B, int ldb,
    float* __restrict__ C, int ldc,
    int M, int Ncols, int K,
    const float* __restrict__ bias, int accumulate)
{
    __shared__ float As[16][64];
    __shared__ float Bs[16][68];
    const int tid = threadIdx.x;
    const int row0 = blockIdx.y * 64;
    const int col0 = blockIdx.x * 64;
    const int tx = tid & 15, ty = tid >> 4;
    const int arow = tid >> 2, acol = (tid & 3) << 2;
    const int brow = tid >> 4, bcol = (tid & 15) << 2;
    float acc[4][4] = {{0.f}};
    for (int k0 = 0; k0 < K; k0 += 16) {
        float4 av = make_float4(0.f, 0.f, 0.f, 0.f);
        if (row0 + arow < M)
            av = *(const float4*)(A + (size_t)(row0 + arow) * lda + k0 + acol);
        As[acol + 0][arow] = av.x;
        As[acol + 1][arow] = av.y;
        As[acol + 2][arow] = av.z;
        As[acol + 3][arow] = av.w;
        float4 bv = *(const float4*)(B + (size_t)(k0 + brow) * ldb + col0 + bcol);
        Bs[brow][bcol + 0] = bv.x;
        Bs[brow][bcol + 1] = bv.y;
        Bs[brow][bcol + 2] = bv.z;
        Bs[brow][bcol + 3] = bv.w;
        __syncthreads();
        #pragma unroll
        for (int k = 0; k < 16; ++k) {
            float a[4], b[4];
            #pragma unroll
            for (int i = 0; i < 4; ++i) a[i] = As[k][ty * 4 + i];
            #pragma unroll
            for (int j = 0; j < 4; ++j) b[j] = Bs[k][tx * 4 + j];
            #pragma unroll
            for (int i = 0; i < 4; ++i)
                #pragma unroll
                for (int j = 0; j < 4; ++j)
                    acc[i][j] = fmaf(a[i], b[j], acc[i][j]);
        }
        __syncthreads();
    }
    #pragma unroll
    for (int i = 0; i < 4; ++i) {
        int r = row0 + ty * 4 + i;
        if (r >= M) continue;
        #pragma unroll
        for (int j = 0; j < 4; ++j) {
            int c = col0 + tx * 4 + j;
            float v = acc[i][j];
            if (bias) v += bias[c];
            float* dst = C + (size_t)r * ldc + c;
            if (accumulate) v += *dst;
            *dst = v;
        }
    }
}

// ---------------- node cross-attention: attn = sigmoid(dot(Q,K)) * V (in place on V) ----------------
__global__ __launch_bounds__(128) void node_attn(const float* __restrict__ Q,
                                                 const float* __restrict__ K,
                                                 float* __restrict__ V)
{
    int nd = blockIdx.x;
    int t = threadIdx.x;
    size_t base = (size_t)nd * HIDD;
    float p = Q[base + t] * K[base + t];
    #pragma unroll
    for (int off = 32; off; off >>= 1) p += __shfl_down(p, off);
    __shared__ float sm[2];
    if ((t & 63) == 0) sm[t >> 6] = p;
    __syncthreads();
    float s = sm[0] + sm[1];
    float sig = 1.f / (1.f + expf(-s));
    V[base + t] *= sig;
}

// ---------------- GAT attention-coefficient dots ----------------
__global__ __launch_bounds__(256) void att_dots1(const float* __restrict__ h1,
    const float* __restrict__ asv, const float* __restrict__ adv,
    float* __restrict__ a_src, float* __restrict__ a_dst)
{
    int nd = blockIdx.x;
    int t = threadIdx.x;
    int w = t >> 6, l = t & 63;
    const float* hr = h1 + (size_t)nd * H1D + w * HIDD;
    const float* sv = asv + w * HIDD;
    const float* dv = adv + w * HIDD;
    float ps = hr[l] * sv[l] + hr[l + 64] * sv[l + 64];
    float pd = hr[l] * dv[l] + hr[l + 64] * dv[l + 64];
    #pragma unroll
    for (int off = 32; off; off >>= 1) {
        ps += __shfl_down(ps, off);
        pd += __shfl_down(pd, off);
    }
    if (l == 0) { a_src[nd * NHEADS + w] = ps; a_dst[nd * NHEADS + w] = pd; }
}

__global__ __launch_bounds__(128) void att_dots2(const float* __restrict__ h2,
    const float* __restrict__ sv, const float* __restrict__ dv,
    float* __restrict__ a_src, float* __restrict__ a_dst)
{
    int nd = blockIdx.x;
    int t = threadIdx.x;
    float hv = h2[(size_t)nd * HIDD + t];
    float ps = hv * sv[t], pd = hv * dv[t];
    #pragma unroll
    for (int off = 32; off; off >>= 1) {
        ps += __shfl_down(ps, off);
        pd += __shfl_down(pd, off);
    }
    __shared__ float sm[4];
    if ((t & 63) == 0) { sm[t >> 6] = ps; sm[2 + (t >> 6)] = pd; }
    __syncthreads();
    if (t == 0) { a_src[nd] = sm[0] + sm[1]; a_dst[nd] = sm[2] + sm[3]; }
}

// ---------------- edge passes ----------------
template<int H>
__global__ __launch_bounds__(256) void edge_max_k(const int* __restrict__ ei,
    const float* __restrict__ asrc, const float* __restrict__ adst, float* __restrict__ amax)
{
    int e = blockIdx.x * 256 + threadIdx.x;
    if (e >= EEDG) return;
    int s, d;
    edge_sd(ei, e, s, d);
    #pragma unroll
    for (int h = 0; h < H; ++h) {
        float a = asrc[s * H + h] + adst[d * H + h];
        a = a >= 0.f ? a : 0.2f * a;
        atomicMaxF(&amax[d * H + h], a);
    }
}

template<int H>
__global__ __launch_bounds__(256) void edge_sum_k(const int* __restrict__ ei,
    const float* __restrict__ asrc, const float* __restrict__ adst,
    const float* __restrict__ amax, float* __restrict__ den, float* __restrict__ exb)
{
    int e = blockIdx.x * 256 + threadIdx.x;
    if (e >= EEDG) return;
    int s, d;
    edge_sd(ei, e, s, d);
    #pragma unroll
    for (int h = 0; h < H; ++h) {
        float a = asrc[s * H + h] + adst[d * H + h];
        a = a >= 0.f ? a : 0.2f * a;
        float m = amax[d * H + h];
        if (!isfinite(m)) m = 0.f;
        float ex = expf(a - m);
        exb[(size_t)e * H + h] = ex;
        atomicAdd(&den[d * H + h], ex);
    }
}

template<int H, int C>
__global__ void edge_msg_k(const int* __restrict__ ei, const float* __restrict__ hsrc,
    const float* __restrict__ exb, const float* __restrict__ den, float* __restrict__ outp)
{
    int e = blockIdx.x;
    int s, d;
    edge_sd(ei, e, s, d);
    __shared__ float att[H];
    int t = threadIdx.x;
    if (t < H) att[t] = exb[(size_t)e * H + t] / (den[d * H + t] + 1e-16f);
    __syncthreads();
    for (int c = t; c < C; c += blockDim.x) {
        atomicAdd(&outp[(size_t)d * C + c], hsrc[(size_t)s * C + c] * att[c >> 7]);
    }
}

// ---------------- graph norm (column stats over N) ----------------
__global__ void colsum(const float* __restrict__ x, float* __restrict__ sums, int n, int rpb)
{
    int C = blockDim.x;
    int c = threadIdx.x;
    int r0 = blockIdx.x * rpb;
    int r1 = min(n, r0 + rpb);
    float s = 0.f;
    for (int r = r0; r < r1; ++r) s += x[(size_t)r * C + c];
    atomicAdd(&sums[c], s);
}

__global__ void center_sq(float* __restrict__ x, const float* __restrict__ sums,
                          const float* __restrict__ ms, float* __restrict__ sq, int n, int rpb)
{
    int C = blockDim.x;
    int c = threadIdx.x;
    float sub = sums[c] * (1.f / n) * ms[c];
    int r0 = blockIdx.x * rpb;
    int r1 = min(n, r0 + rpb);
    float acc = 0.f;
    for (int r = r0; r < r1; ++r) {
        float v = x[(size_t)r * C + c] - sub;
        x[(size_t)r * C + c] = v;
        acc += v * v;
    }
    atomicAdd(&sq[c], acc);
}

__global__ void scale_elu(float* __restrict__ x, const float* __restrict__ sq,
                          const float* __restrict__ w, const float* __restrict__ b, int n, int rpb)
{
    int C = blockDim.x;
    int c = threadIdx.x;
    float inv = rsqrtf(sq[c] * (1.f / n) + 1e-5f);
    float wc = w[c] * inv, bc = b[c];
    int r0 = blockIdx.x * rpb;
    int r1 = min(n, r0 + rpb);
    for (int r = r0; r < r1; ++r) {
        float v = x[(size_t)r * C + c] * wc + bc;
        x[(size_t)r * C + c] = v > 0.f ? v : expm1f(v);
    }
}

// ---------------- final projection (128 -> 2) ----------------
__global__ __launch_bounds__(128) void final_proj(const float* __restrict__ x,
    const float* __restrict__ Wn, const float* __restrict__ bn, float* __restrict__ out)
{
    int nd = blockIdx.x;
    int t = threadIdx.x;
    float v = x[(size_t)nd * HIDD + t];
    float p0 = v * Wn[t * 2], p1 = v * Wn[t * 2 + 1];
    #pragma unroll
    for (int off = 32; off; off >>= 1) {
        p0 += __shfl_down(p0, off);
        p1 += __shfl_down(p1, off);
    }
    __shared__ float sm[4];
    if ((t & 63) == 0) { sm[t >> 6] = p0; sm[2 + (t >> 6)] = p1; }
    __syncthreads();
    if (t == 0) {
        out[nd * 2 + 0] = sm[0] + sm[1] + bn[0];
        out[nd * 2 + 1] = sm[2] + sm[3] + bn[1];
    }
}

// ---------------- host launch ----------------
extern "C" void kernel_launch(void* const* d_in, const int* in_sizes, int n_in,
                              void* d_out, int out_size, void* d_ws, size_t ws_size,
                              hipStream_t stream)
{
    const float* x   = (const float*)d_in[0];
    const int*   ei  = (const int*)d_in[1];
    const float* Wq  = (const float*)d_in[2];
    const float* Wk  = (const float*)d_in[3];
    const float* Wv  = (const float*)d_in[4];
    const float* Wo  = (const float*)d_in[5];
    const float* bo  = (const float*)d_in[6];
    const float* W1  = (const float*)d_in[7];
    const float* as1 = (const float*)d_in[8];
    const float* ad1 = (const float*)d_in[9];
    const float* b1  = (const float*)d_in[10];
    const float* g1w = (const float*)d_in[11];
    const float* g1b = (const float*)d_in[12];
    const float* g1m = (const float*)d_in[13];
    const float* W2  = (const float*)d_in[14];
    const float* as2 = (const float*)d_in[15];
    const float* ad2 = (const float*)d_in[16];
    const float* b2  = (const float*)d_in[17];
    const float* g2w = (const float*)d_in[18];
    const float* g2b = (const float*)d_in[19];
    const float* g2m = (const float*)d_in[20];
    const float* Wn  = (const float*)d_in[21];
    const float* bn  = (const float*)d_in[22];
    float* out = (float*)d_out;

    float* ws = (float*)d_ws;
    const size_t n = NN;
    size_t off = 0;
    float* h1   = ws + off; off += n * 512;   // later reused as h2
    float* o1   = ws + off; off += n * 512;
    float* Qb   = ws + off; off += n * 128;   // later h0
    float* Kb   = ws + off; off += n * 128;   // later o2
    float* Vb   = ws + off; off += n * 128;   // attn, later exp buffer
    float* asrc = ws + off; off += n * 4;
    float* adst = ws + off; off += n * 4;
    float* amax = ws + off; off += n * 4;
    float* den  = ws + off; off += n * 4;
    float* msum = ws + off; off += 512;
    float* vsum = ws + off; off += 512;
    float* h0  = Qb;
    float* h2  = h1;
    float* o2  = Kb;
    float* exb = Vb;

    const int MB = (NN + 63) / 64;           // 782 row tiles
    dim3 blk(256);

    // --- cross attention: Q,K,V, sigmoid gate ---
    gemm_f32<<<dim3(HIDD / 64, MB), blk, 0, stream>>>(x,         INDIM, Wq, HIDD, Qb, HIDD, NN, HIDD, SDIM, nullptr, 0);
    gemm_f32<<<dim3(HIDD / 64, MB), blk, 0, stream>>>(x + SDIM,  INDIM, Wk, HIDD, Kb, HIDD, NN, HIDD, MDIM, nullptr, 0);
    gemm_f32<<<dim3(HIDD / 64, MB), blk, 0, stream>>>(x + SDIM,  INDIM, Wv, HIDD, Vb, HIDD, NN, HIDD, MDIM, nullptr, 0);
    node_attn<<<NN, 128, 0, stream>>>(Qb, Kb, Vb);

    // --- h0 = [x_struct | attn] @ Wo + bo ---
    gemm_f32<<<dim3(SDIM / 64, MB), blk, 0, stream>>>(x,  INDIM, Wo,               SDIM, h0, SDIM, NN, SDIM, SDIM, bo, 0);
    gemm_f32<<<dim3(SDIM / 64, MB), blk, 0, stream>>>(Vb, HIDD,  Wo + SDIM * SDIM, SDIM, h0, SDIM, NN, SDIM, HIDD, nullptr, 1);

    // --- h1 = [h0 | x_sem] @ W1 ---
    gemm_f32<<<dim3(H1D / 64, MB), blk, 0, stream>>>(h0,       SDIM,  W1,              H1D, h1, H1D, NN, H1D, SDIM, nullptr, 0);
    gemm_f32<<<dim3(H1D / 64, MB), blk, 0, stream>>>(x + SDIM, INDIM, W1 + SDIM * H1D, H1D, h1, H1D, NN, H1D, MDIM, nullptr, 1);

    // --- GAT layer 1 ---
    att_dots1<<<NN, 256, 0, stream>>>(h1, as1, ad1, asrc, adst);
    fillk<<<512, 256, 0, stream>>>(amax, -INFINITY, (long)NN * NHEADS);
    fillk<<<512, 256, 0, stream>>>(den, 0.f, (long)NN * NHEADS);
    edge_max_k<NHEADS><<<(EEDG + 255) / 256, 256, 0, stream>>>(ei, asrc, adst, amax);
    edge_sum_k<NHEADS><<<(EEDG + 255) / 256, 256, 0, stream>>>(ei, asrc, adst, amax, den, exb);
    rowinit<<<2048, 256, 0, stream>>>(o1, b1, (long)NN * H1D, H1D - 1);
    edge_msg_k<NHEADS, H1D><<<EEDG, 256, 0, stream>>>(ei, h1, exb, den, o1);

    // --- graph norm 1 + ELU ---
    fillk<<<4, 256, 0, stream>>>(msum, 0.f, 1024);
    colsum<<<(NN + 127) / 128, H1D, 0, stream>>>(o1, msum, NN, 128);
    center_sq<<<(NN + 127) / 128, H1D, 0, stream>>>(o1, msum, g1m, vsum, NN, 128);
    scale_elu<<<(NN + 127) / 128, H1D, 0, stream>>>(o1, vsum, g1w, g1b, NN, 128);

    // --- GAT layer 2 ---
    gemm_f32<<<dim3(HIDD / 64, MB), blk, 0, stream>>>(o1, H1D, W2, HIDD, h2, HIDD, NN, HIDD, H1D, nullptr, 0);
    att_dots2<<<NN, 128, 0, stream>>>(h2, as2, ad2, asrc, adst);
    fillk<<<512, 256, 0, stream>>>(amax, -INFINITY, (long)NN);
    fillk<<<512, 256, 0, stream>>>(den, 0.f, (long)NN);
    edge_max_k<1><<<(EEDG + 255) / 256, 256, 0, stream>>>(ei, asrc, adst, amax);
    edge_sum_k<1><<<(EEDG + 255) / 256, 256, 0, stream>>>(ei, asrc, adst, amax, den, exb);
    rowinit<<<2048, 256, 0, stream>>>(o2, b2, (long)NN * HIDD, HIDD - 1);
    edge_msg_k<1, HIDD><<<EEDG, 128, 0, stream>>>(ei, h2, exb, den, o2);

    // --- graph norm 2 + ELU ---
    fillk<<<4, 256, 0, stream>>>(msum, 0.f, 1024);
    colsum<<<(NN + 127) / 128, HIDD, 0, stream>>>(o2, msum, NN, 128);
    center_sq<<<(NN + 127) / 128, HIDD, 0, stream>>>(o2, msum, g2m, vsum, NN, 128);
    scale_elu<<<(NN + 127) / 128, HIDD, 0, stream>>>(o2, vsum, g2w, g2b, NN, 128);

    // --- output projection ---
    final_proj<<<NN, 128, 0, stream>>>(o2, Wn, bn, out);
}

// Round 2
// 2005.448 us; speedup vs baseline: 1.4926x; 1.4926x over previous
//
#include <hip/hip_runtime.h>
#include <math.h>

#define NN 50000
#define NE 500000
#define EEDG 550000          // NE + NN self loops
#define SDIM 128             // STRUCT
#define MDIM 768             // SEM
#define HIDD 128             // HID
#define NHEADS 4
#define INDIM 896            // STRUCT + SEM
#define H1D 512              // HEADS*HID
#define SCAN_NB 196          // ceil(NN/256)

// ---------------- utility ----------------
__device__ __forceinline__ void edge_sd(const int* __restrict__ ei, int e, int& s, int& d) {
    if (e < NE) { s = ei[e]; d = ei[NE + e]; }
    else        { s = e - NE; d = e - NE; }
}

__global__ void fillk(float* __restrict__ p, float v, long count) {
    long i = (long)blockIdx.x * blockDim.x + threadIdx.x;
    long stride = (long)gridDim.x * blockDim.x;
    for (; i < count; i += stride) p[i] = v;
}

__global__ void fillk_i(int* __restrict__ p, int v, long count) {
    long i = (long)blockIdx.x * blockDim.x + threadIdx.x;
    long stride = (long)gridDim.x * blockDim.x;
    for (; i < count; i += stride) p[i] = v;
}

// ---------------- CSR build ----------------
__global__ __launch_bounds__(256) void count_deg(const int* __restrict__ ei, int* __restrict__ deg) {
    int e = blockIdx.x * 256 + threadIdx.x;
    if (e >= EEDG) return;
    int d = e < NE ? ei[NE + e] : e - NE;
    atomicAdd(&deg[d], 1);
}

__global__ __launch_bounds__(256) void scan_bsum(const int* __restrict__ deg, int* __restrict__ part) {
    __shared__ int s[256];
    int t = threadIdx.x;
    int idx = blockIdx.x * 256 + t;
    s[t] = idx < NN ? deg[idx] : 0;
    __syncthreads();
    for (int off = 128; off; off >>= 1) {
        if (t < off) s[t] += s[t + off];
        __syncthreads();
    }
    if (t == 0) part[blockIdx.x] = s[0];
}

__global__ __launch_bounds__(256) void scan_part(int* __restrict__ part) {
    __shared__ int s[256];
    int t = threadIdx.x;
    int v = t < SCAN_NB ? part[t] : 0;
    s[t] = v;
    __syncthreads();
    for (int off = 1; off < 256; off <<= 1) {
        int x = t >= off ? s[t - off] : 0;
        __syncthreads();
        s[t] += x;
        __syncthreads();
    }
    if (t < SCAN_NB) part[t] = s[t] - v;   // exclusive
}

__global__ __launch_bounds__(256) void scan_write(const int* __restrict__ deg, const int* __restrict__ part,
                                                  int* __restrict__ rowptr) {
    __shared__ int s[256];
    int t = threadIdx.x;
    int idx = blockIdx.x * 256 + t;
    int v = idx < NN ? deg[idx] : 0;
    s[t] = v;
    __syncthreads();
    for (int off = 1; off < 256; off <<= 1) {
        int x = t >= off ? s[t - off] : 0;
        __syncthreads();
        s[t] += x;
        __syncthreads();
    }
    if (idx < NN) rowptr[idx] = part[blockIdx.x] + s[t] - v;
    if (idx == NN - 1) rowptr[NN] = EEDG;
}

__global__ __launch_bounds__(256) void fill_csr(const int* __restrict__ ei, const int* __restrict__ rowptr,
                                                int* __restrict__ cur, int* __restrict__ esrc,
                                                int* __restrict__ eidx) {
    int e = blockIdx.x * 256 + threadIdx.x;
    if (e >= EEDG) return;
    int s, d;
    edge_sd(ei, e, s, d);
    int p = rowptr[d] + atomicAdd(&cur[d], 1);
    esrc[p] = s;
    eidx[p] = e;
}

// ---------------- GEMM: C[M x Ncols] = A[M x K] @ B[K x Ncols] (+bias)(+=C) ----------------
__global__ __launch_bounds__(256) void gemm_f32(
    const float* __restrict__ A, int lda,
    const float* __restrict__ B, int ldb,
    float* __restrict__ C, int ldc,
    int M, int Ncols, int K,
    const float* __restrict__ bias, int accumulate)
{
    __shared__ float As[16][64];
    __shared__ float Bs[16][68];
    const int tid = threadIdx.x;
    const int row0 = blockIdx.y * 64;
    const int col0 = blockIdx.x * 64;
    const int tx = tid & 15, ty = tid >> 4;
    const int arow = tid >> 2, acol = (tid & 3) << 2;
    const int brow = tid >> 4, bcol = (tid & 15) << 2;
    float acc[4][4] = {{0.f}};
    for (int k0 = 0; k0 < K; k0 += 16) {
        float4 av = make_float4(0.f, 0.f, 0.f, 0.f);
        if (row0 + arow < M)
            av = *(const float4*)(A + (size_t)(row0 + arow) * lda + k0 + acol);
        As[acol + 0][arow] = av.x;
        As[acol + 1][arow] = av.y;
        As[acol + 2][arow] = av.z;
        As[acol + 3][arow] = av.w;
        float4 bv = *(const float4*)(B + (size_t)(k0 + brow) * ldb + col0 + bcol);
        Bs[brow][bcol + 0] = bv.x;
        Bs[brow][bcol + 1] = bv.y;
        Bs[brow][bcol + 2] = bv.z;
        Bs[brow][bcol + 3] = bv.w;
        __syncthreads();
        #pragma unroll
        for (int k = 0; k < 16; ++k) {
            float a[4], b[4];
            #pragma unroll
            for (int i = 0; i < 4; ++i) a[i] = As[k][ty * 4 + i];
            #pragma unroll
            for (int j = 0; j < 4; ++j) b[j] = Bs[k][tx * 4 + j];
            #pragma unroll
            for (int i = 0; i < 4; ++i)
                #pragma unroll
                for (int j = 0; j < 4; ++j)
                    acc[i][j] = fmaf(a[i], b[j], acc[i][j]);
        }
        __syncthreads();
    }
    #pragma unroll
    for (int i = 0; i < 4; ++i) {
        int r = row0 + ty * 4 + i;
        if (r >= M) continue;
        #pragma unroll
        for (int j = 0; j < 4; ++j) {
            int c = col0 + tx * 4 + j;
            float v = acc[i][j];
            if (bias) v += bias[c];
            float* dst = C + (size_t)r * ldc + c;
            if (accumulate) v += *dst;
            *dst = v;
        }
    }
}

// ---------------- node cross-attention: attn = sigmoid(dot(Q,K)) * V (in place on V) ----------------
__global__ __launch_bounds__(128) void node_attn(const float* __restrict__ Q,
                                                 const float* __restrict__ K,
                                                 float* __restrict__ V)
{
    int nd = blockIdx.x;
    int t = threadIdx.x;
    size_t base = (size_t)nd * HIDD;
    float p = Q[base + t] * K[base + t];
    #pragma unroll
    for (int off = 32; off; off >>= 1) p += __shfl_down(p, off);
    __shared__ float sm[2];
    if ((t & 63) == 0) sm[t >> 6] = p;
    __syncthreads();
    float s = sm[0] + sm[1];
    float sig = 1.f / (1.f + expf(-s));
    V[base + t] *= sig;
}

// ---------------- GAT attention-coefficient dots ----------------
__global__ __launch_bounds__(256) void att_dots1(const float* __restrict__ h1,
    const float* __restrict__ asv, const float* __restrict__ adv,
    float* __restrict__ a_src, float* __restrict__ a_dst)
{
    int nd = blockIdx.x;
    int t = threadIdx.x;
    int w = t >> 6, l = t & 63;
    const float* hr = h1 + (size_t)nd * H1D + w * HIDD;
    const float* sv = asv + w * HIDD;
    const float* dv = adv + w * HIDD;
    float ps = hr[l] * sv[l] + hr[l + 64] * sv[l + 64];
    float pd = hr[l] * dv[l] + hr[l + 64] * dv[l + 64];
    #pragma unroll
    for (int off = 32; off; off >>= 1) {
        ps += __shfl_down(ps, off);
        pd += __shfl_down(pd, off);
    }
    if (l == 0) { a_src[nd * NHEADS + w] = ps; a_dst[nd * NHEADS + w] = pd; }
}

__global__ __launch_bounds__(128) void att_dots2(const float* __restrict__ h2,
    const float* __restrict__ sv, const float* __restrict__ dv,
    float* __restrict__ a_src, float* __restrict__ a_dst)
{
    int nd = blockIdx.x;
    int t = threadIdx.x;
    float hv = h2[(size_t)nd * HIDD + t];
    float ps = hv * sv[t], pd = hv * dv[t];
    #pragma unroll
    for (int off = 32; off; off >>= 1) {
        ps += __shfl_down(ps, off);
        pd += __shfl_down(pd, off);
    }
    __shared__ float sm[4];
    if ((t & 63) == 0) { sm[t >> 6] = ps; sm[2 + (t >> 6)] = pd; }
    __syncthreads();
    if (t == 0) { a_src[nd] = sm[0] + sm[1]; a_dst[nd] = sm[2] + sm[3]; }
}

// ---------------- edge exp+denominator pass (max subtraction cancels; alphas are O(1)) ----------------
template<int H>
__global__ __launch_bounds__(256) void edge_sum_k(const int* __restrict__ ei,
    const float* __restrict__ asrc, const float* __restrict__ adst,
    float* __restrict__ den, float* __restrict__ exb)
{
    int e = blockIdx.x * 256 + threadIdx.x;
    if (e >= EEDG) return;
    int s, d;
    edge_sd(ei, e, s, d);
    #pragma unroll
    for (int h = 0; h < H; ++h) {
        float a = asrc[s * H + h] + adst[d * H + h];
        a = a >= 0.f ? a : 0.2f * a;
        float ex = expf(a);
        exb[(size_t)e * H + h] = ex;
        atomicAdd(&den[d * H + h], ex);
    }
}

// ---------------- gather aggregation (CSR): out[d,c] = sum_e att[e,h]*h[src,c] + bias[c] ----------------
template<int H, int C>
__global__ void agg_k(const int* __restrict__ rowptr, const int* __restrict__ esrc,
                      const int* __restrict__ eidx, const float* __restrict__ hsrc,
                      const float* __restrict__ exb, const float* __restrict__ den,
                      const float* __restrict__ bias, float* __restrict__ outp)
{
    int d = blockIdx.x;
    int c = threadIdx.x;          // blockDim == C
    int h = c >> 7;               // C/H == 128
    int beg = rowptr[d], end = rowptr[d + 1];
    float invd = 1.f / (den[d * H + h] + 1e-16f);
    float acc = 0.f;
    for (int i = beg; i < end; ++i) {
        int s = esrc[i];
        int e = eidx[i];
        float att = exb[(size_t)e * H + h] * invd;
        acc = fmaf(hsrc[(size_t)s * C + c], att, acc);
    }
    outp[(size_t)d * C + c] = acc + bias[c];
}

// ---------------- graph norm (fused 2-pass) ----------------
__global__ void colstat(const float* __restrict__ x, float* __restrict__ msum,
                        float* __restrict__ vsum, int n, int rpb)
{
    int C = blockDim.x;
    int c = threadIdx.x;
    int r0 = blockIdx.x * rpb;
    int r1 = min(n, r0 + rpb);
    float s = 0.f, s2 = 0.f;
    for (int r = r0; r < r1; ++r) {
        float v = x[(size_t)r * C + c];
        s += v;
        s2 += v * v;
    }
    atomicAdd(&msum[c], s);
    atomicAdd(&vsum[c], s2);
}

__global__ void apply_norm_elu(float* __restrict__ x, const float* __restrict__ msum,
                               const float* __restrict__ vsum, const float* __restrict__ ms,
                               const float* __restrict__ w, const float* __restrict__ b,
                               int n, int rpb)
{
    int C = blockDim.x;
    int c = threadIdx.x;
    const float invn = 1.f / (float)NN;
    float mean = msum[c] * invn;
    float sub = mean * ms[c];
    float var = vsum[c] * invn - 2.f * sub * mean + sub * sub;
    float inv = rsqrtf(var + 1e-5f);
    float wc = w[c] * inv, bc = b[c];
    int r0 = blockIdx.x * rpb;
    int r1 = min(n, r0 + rpb);
    for (int r = r0; r < r1; ++r) {
        float v = (x[(size_t)r * C + c] - sub) * wc + bc;
        x[(size_t)r * C + c] = v > 0.f ? v : expm1f(v);
    }
}

// ---------------- final projection (128 -> 2) ----------------
__global__ __launch_bounds__(128) void final_proj(const float* __restrict__ x,
    const float* __restrict__ Wn, const float* __restrict__ bn, float* __restrict__ out)
{
    int nd = blockIdx.x;
    int t = threadIdx.x;
    float v = x[(size_t)nd * HIDD + t];
    float p0 = v * Wn[t * 2], p1 = v * Wn[t * 2 + 1];
    #pragma unroll
    for (int off = 32; off; off >>= 1) {
        p0 += __shfl_down(p0, off);
        p1 += __shfl_down(p1, off);
    }
    __shared__ float sm[4];
    if ((t & 63) == 0) { sm[t >> 6] = p0; sm[2 + (t >> 6)] = p1; }
    __syncthreads();
    if (t == 0) {
        out[nd * 2 + 0] = sm[0] + sm[1] + bn[0];
        out[nd * 2 + 1] = sm[2] + sm[3] + bn[1];
    }
}

// ---------------- host launch ----------------
extern "C" void kernel_launch(void* const* d_in, const int* in_sizes, int n_in,
                              void* d_out, int out_size, void* d_ws, size_t ws_size,
                              hipStream_t stream)
{
    const float* x   = (const float*)d_in[0];
    const int*   ei  = (const int*)d_in[1];
    const float* Wq  = (const float*)d_in[2];
    const float* Wk  = (const float*)d_in[3];
    const float* Wv  = (const float*)d_in[4];
    const float* Wo  = (const float*)d_in[5];
    const float* bo  = (const float*)d_in[6];
    const float* W1  = (const float*)d_in[7];
    const float* as1 = (const float*)d_in[8];
    const float* ad1 = (const float*)d_in[9];
    const float* b1  = (const float*)d_in[10];
    const float* g1w = (const float*)d_in[11];
    const float* g1b = (const float*)d_in[12];
    const float* g1m = (const float*)d_in[13];
    const float* W2  = (const float*)d_in[14];
    const float* as2 = (const float*)d_in[15];
    const float* ad2 = (const float*)d_in[16];
    const float* b2  = (const float*)d_in[17];
    const float* g2w = (const float*)d_in[18];
    const float* g2b = (const float*)d_in[19];
    const float* g2m = (const float*)d_in[20];
    const float* Wn  = (const float*)d_in[21];
    const float* bn  = (const float*)d_in[22];
    float* out = (float*)d_out;

    float* ws = (float*)d_ws;
    const size_t n = NN;
    size_t off = 0;
    float* h1   = ws + off; off += n * 512;   // later reused as h2
    float* o1   = ws + off; off += n * 512;
    float* Qb   = ws + off; off += n * 128;   // later h0
    float* Kb   = ws + off; off += n * 128;   // later o2
    float* Vb   = ws + off; off += n * 128;   // attn gate output; later exb (2.2M <= 6.4M)
    float* asrc = ws + off; off += n * 4;
    float* adst = ws + off; off += n * 4;
    float* den  = ws + off; off += n * 4;
    float* msum = ws + off; off += 512;
    float* vsum = ws + off; off += 512;
    int* iws    = (int*)(ws + off);
    size_t ioff = 0;
    int* rowptr = iws + ioff; ioff += NN + 1;
    int* degcur = iws + ioff; ioff += NN;      // deg, then reused as fill cursor
    int* esrc   = iws + ioff; ioff += EEDG;
    int* eidx   = iws + ioff; ioff += EEDG;
    int* spart  = iws + ioff; ioff += 256;
    float* h0  = Qb;
    float* h2  = h1;
    float* o2  = Kb;
    float* exb = Vb;

    const int MB = (NN + 63) / 64;
    const int EB = (EEDG + 255) / 256;
    dim3 blk(256);

    // --- CSR build (depends only on edge_index) ---
    fillk_i<<<196, 256, 0, stream>>>(degcur, 0, NN);
    count_deg<<<EB, 256, 0, stream>>>(ei, degcur);
    scan_bsum<<<SCAN_NB, 256, 0, stream>>>(degcur, spart);
    scan_part<<<1, 256, 0, stream>>>(spart);
    scan_write<<<SCAN_NB, 256, 0, stream>>>(degcur, spart, rowptr);
    fillk_i<<<196, 256, 0, stream>>>(degcur, 0, NN);
    fill_csr<<<EB, 256, 0, stream>>>(ei, rowptr, degcur, esrc, eidx);

    // --- cross attention: Q,K,V, sigmoid gate ---
    gemm_f32<<<dim3(HIDD / 64, MB), blk, 0, stream>>>(x,        INDIM, Wq, HIDD, Qb, HIDD, NN, HIDD, SDIM, nullptr, 0);
    gemm_f32<<<dim3(HIDD / 64, MB), blk, 0, stream>>>(x + SDIM, INDIM, Wk, HIDD, Kb, HIDD, NN, HIDD, MDIM, nullptr, 0);
    gemm_f32<<<dim3(HIDD / 64, MB), blk, 0, stream>>>(x + SDIM, INDIM, Wv, HIDD, Vb, HIDD, NN, HIDD, MDIM, nullptr, 0);
    node_attn<<<NN, 128, 0, stream>>>(Qb, Kb, Vb);

    // --- h0 = [x_struct | attn] @ Wo + bo ---
    gemm_f32<<<dim3(SDIM / 64, MB), blk, 0, stream>>>(x,  INDIM, Wo,               SDIM, h0, SDIM, NN, SDIM, SDIM, bo, 0);
    gemm_f32<<<dim3(SDIM / 64, MB), blk, 0, stream>>>(Vb, HIDD,  Wo + SDIM * SDIM, SDIM, h0, SDIM, NN, SDIM, HIDD, nullptr, 1);

    // --- h1 = [h0 | x_sem] @ W1 ---
    gemm_f32<<<dim3(H1D / 64, MB), blk, 0, stream>>>(h0,       SDIM,  W1,              H1D, h1, H1D, NN, H1D, SDIM, nullptr, 0);
    gemm_f32<<<dim3(H1D / 64, MB), blk, 0, stream>>>(x + SDIM, INDIM, W1 + SDIM * H1D, H1D, h1, H1D, NN, H1D, MDIM, nullptr, 1);

    // --- GAT layer 1 ---
    att_dots1<<<NN, 256, 0, stream>>>(h1, as1, ad1, asrc, adst);
    fillk<<<196, 256, 0, stream>>>(den, 0.f, (long)NN * NHEADS);
    edge_sum_k<NHEADS><<<EB, 256, 0, stream>>>(ei, asrc, adst, den, exb);
    agg_k<NHEADS, H1D><<<NN, H1D, 0, stream>>>(rowptr, esrc, eidx, h1, exb, den, b1, o1);

    // --- graph norm 1 + ELU ---
    fillk<<<4, 256, 0, stream>>>(msum, 0.f, 1024);
    colstat<<<(NN + 127) / 128, H1D, 0, stream>>>(o1, msum, vsum, NN, 128);
    apply_norm_elu<<<(NN + 127) / 128, H1D, 0, stream>>>(o1, msum, vsum, g1m, g1w, g1b, NN, 128);

    // --- GAT layer 2 ---
    gemm_f32<<<dim3(HIDD / 64, MB), blk, 0, stream>>>(o1, H1D, W2, HIDD, h2, HIDD, NN, HIDD, H1D, nullptr, 0);
    att_dots2<<<NN, 128, 0, stream>>>(h2, as2, ad2, asrc, adst);
    fillk<<<196, 256, 0, stream>>>(den, 0.f, (long)NN);
    edge_sum_k<1><<<EB, 256, 0, stream>>>(ei, asrc, adst, den, exb);
    agg_k<1, HIDD><<<NN, HIDD, 0, stream>>>(rowptr, esrc, eidx, h2, exb, den, b2, o2);

    // --- graph norm 2 + ELU ---
    fillk<<<4, 256, 0, stream>>>(msum, 0.f, 1024);
    colstat<<<(NN + 127) / 128, HIDD, 0, stream>>>(o2, msum, vsum, NN, 128);
    apply_norm_elu<<<(NN + 127) / 128, HIDD, 0, stream>>>(o2, msum, vsum, g2m, g2w, g2b, NN, 128);

    // --- output projection ---
    final_proj<<<NN, 128, 0, stream>>>(o2, Wn, bn, out);
}

// Round 3
// 950.681 us; speedup vs baseline: 3.1487x; 2.1095x over previous
//
#include <hip/hip_runtime.h>
#include <math.h>

#define NN 50000
#define NE 500000
#define EEDG 550000          // NE + NN self loops
#define SDIM 128             // STRUCT
#define MDIM 768             // SEM
#define HIDD 128             // HID
#define NHEADS 4
#define INDIM 896            // STRUCT + SEM
#define H1D 512              // HEADS*HID
#define SCAN_NB 196          // ceil(NN/256)
#define MP 50048             // NN padded to 128*391
#define MT 391               // row tiles of 128

typedef unsigned short u16;
typedef unsigned int u32;
typedef __attribute__((ext_vector_type(8))) short short8;
typedef __attribute__((ext_vector_type(4))) float f32x4;

// ---------------- bf16 helpers ----------------
__device__ __forceinline__ u16 f2bf(float f) {
    union { float f; u32 u; } v; v.f = f;
    u32 r = v.u + 0x7FFFu + ((v.u >> 16) & 1u);
    return (u16)(r >> 16);
}
__device__ __forceinline__ float bf2f(u16 h) {
    union { u32 u; float f; } v; v.u = ((u32)h) << 16;
    return v.f;
}

__device__ __forceinline__ void gl_lds16(const u16* g, u16* l) {
    __builtin_amdgcn_global_load_lds(
        (const __attribute__((address_space(1))) void*)g,
        (__attribute__((address_space(3))) void*)l, 16, 0, 0);
}

// ---------------- utility ----------------
__device__ __forceinline__ void edge_sd(const int* __restrict__ ei, int e, int& s, int& d) {
    if (e < NE) { s = ei[e]; d = ei[NE + e]; }
    else        { s = e - NE; d = e - NE; }
}

__global__ void fillk(float* __restrict__ p, float v, long count) {
    long i = (long)blockIdx.x * blockDim.x + threadIdx.x;
    long stride = (long)gridDim.x * blockDim.x;
    for (; i < count; i += stride) p[i] = v;
}

__global__ void fillk_i(int* __restrict__ p, int v, long count) {
    long i = (long)blockIdx.x * blockDim.x + threadIdx.x;
    long stride = (long)gridDim.x * blockDim.x;
    for (; i < count; i += stride) p[i] = v;
}

// ---------------- casts ----------------
// x (NN x 896 f32) -> xb (MP x 896 bf16), pad rows zero. 4 elems/thread.
__global__ __launch_bounds__(256) void cast_pad_x(const float4* __restrict__ x4, u16* __restrict__ xb) {
    const long total = (long)MP * 224;
    long i = (long)blockIdx.x * blockDim.x + threadIdx.x;
    long stride = (long)gridDim.x * blockDim.x;
    for (; i < total; i += stride) {
        int row = (int)(i / 224);
        int c4 = (int)(i - (long)row * 224);
        float4 v = make_float4(0.f, 0.f, 0.f, 0.f);
        if (row < NN) v = x4[(size_t)row * 224 + c4];
        short4 o;
        o.x = (short)f2bf(v.x); o.y = (short)f2bf(v.y);
        o.z = (short)f2bf(v.z); o.w = (short)f2bf(v.w);
        *(short4*)(xb + (size_t)row * 896 + c4 * 4) = o;
    }
}

// W (K x N f32, row-major) -> Wb (N x K bf16) transposed cast
__global__ __launch_bounds__(256) void cast_wT(const float* __restrict__ W, u16* __restrict__ Wb, int K, int N) {
    int k = blockIdx.x * 4 + (threadIdx.x >> 6);
    int n = blockIdx.y * 64 + (threadIdx.x & 63);
    if (k < K && n < N) Wb[(size_t)n * K + k] = f2bf(W[(size_t)k * N + n]);
}

// ---------------- CSR build ----------------
__global__ __launch_bounds__(256) void count_deg(const int* __restrict__ ei, int* __restrict__ deg) {
    int e = blockIdx.x * 256 + threadIdx.x;
    if (e >= EEDG) return;
    int d = e < NE ? ei[NE + e] : e - NE;
    atomicAdd(&deg[d], 1);
}

__global__ __launch_bounds__(256) void scan_bsum(const int* __restrict__ deg, int* __restrict__ part) {
    __shared__ int s[256];
    int t = threadIdx.x;
    int idx = blockIdx.x * 256 + t;
    s[t] = idx < NN ? deg[idx] : 0;
    __syncthreads();
    for (int off = 128; off; off >>= 1) {
        if (t < off) s[t] += s[t + off];
        __syncthreads();
    }
    if (t == 0) part[blockIdx.x] = s[0];
}

__global__ __launch_bounds__(256) void scan_part(int* __restrict__ part) {
    __shared__ int s[256];
    int t = threadIdx.x;
    int v = t < SCAN_NB ? part[t] : 0;
    s[t] = v;
    __syncthreads();
    for (int off = 1; off < 256; off <<= 1) {
        int x = t >= off ? s[t - off] : 0;
        __syncthreads();
        s[t] += x;
        __syncthreads();
    }
    if (t < SCAN_NB) part[t] = s[t] - v;   // exclusive
}

__global__ __launch_bounds__(256) void scan_write(const int* __restrict__ deg, const int* __restrict__ part,
                                                  int* __restrict__ rowptr) {
    __shared__ int s[256];
    int t = threadIdx.x;
    int idx = blockIdx.x * 256 + t;
    int v = idx < NN ? deg[idx] : 0;
    s[t] = v;
    __syncthreads();
    for (int off = 1; off < 256; off <<= 1) {
        int x = t >= off ? s[t - off] : 0;
        __syncthreads();
        s[t] += x;
        __syncthreads();
    }
    if (idx < NN) rowptr[idx] = part[blockIdx.x] + s[t] - v;
    if (idx == NN - 1) rowptr[NN] = EEDG;
}

__global__ __launch_bounds__(256) void fill_csr(const int* __restrict__ ei, const int* __restrict__ rowptr,
                                                int* __restrict__ cur, int* __restrict__ esrc,
                                                int* __restrict__ eidx) {
    int e = blockIdx.x * 256 + threadIdx.x;
    if (e >= EEDG) return;
    int s, d;
    edge_sd(ei, e, s, d);
    int p = rowptr[d] + atomicAdd(&cur[d], 1);
    esrc[p] = s;
    eidx[p] = e;
}

// ---------------- MFMA bf16 GEMM ----------------
// C[MP x N] = [A1 (K1 cols) | A2 (K2 cols)] @ B^T   (B stored N x K bf16)
// 128x128 tile, BK=32, 4 waves 2x2, mfma_f32_16x16x32_bf16.
template<int OUT_BF16>
__global__ __launch_bounds__(256) void gemm_mfma(
    const u16* __restrict__ A1, int lda1, int K1,
    const u16* __restrict__ A2, int lda2, int K2,
    const u16* __restrict__ Bw,
    void* __restrict__ Cout, int ldc,
    const float* __restrict__ bias)
{
    __shared__ u16 Asm[128 * 32];
    __shared__ u16 Bsm[128 * 32];
    const int tid = threadIdx.x;
    const int wave = tid >> 6, lane = tid & 63;
    const int wr = wave >> 1, wc = wave & 1;
    const int row0 = blockIdx.y * 128;
    const int col0 = blockIdx.x * 128;
    const int K = K1 + K2;
    const int srow = tid >> 2;
    const int skp = (tid & 3) * 8;
    const int l15 = lane & 15, l4 = lane >> 4;

    f32x4 acc[4][4];
    #pragma unroll
    for (int i = 0; i < 4; ++i)
        #pragma unroll
        for (int j = 0; j < 4; ++j)
            acc[i][j] = (f32x4){0.f, 0.f, 0.f, 0.f};

    for (int k0 = 0; k0 < K; k0 += 32) {
        const u16* Ab; int la; int kk;
        if (k0 < K1) { Ab = A1; la = lda1; kk = k0; }
        else         { Ab = A2; la = lda2; kk = k0 - K1; }
        gl_lds16(Ab + (size_t)(row0 + srow) * la + kk + skp,      Asm + srow * 32 + skp);
        gl_lds16(Ab + (size_t)(row0 + srow + 64) * la + kk + skp, Asm + (srow + 64) * 32 + skp);
        gl_lds16(Bw + (size_t)(col0 + srow) * K + k0 + skp,       Bsm + srow * 32 + skp);
        gl_lds16(Bw + (size_t)(col0 + srow + 64) * K + k0 + skp,  Bsm + (srow + 64) * 32 + skp);
        __syncthreads();
        short8 af[4], bfr[4];
        #pragma unroll
        for (int m = 0; m < 4; ++m)
            af[m] = *(const short8*)(Asm + (wr * 64 + m * 16 + l15) * 32 + l4 * 8);
        #pragma unroll
        for (int n = 0; n < 4; ++n)
            bfr[n] = *(const short8*)(Bsm + (wc * 64 + n * 16 + l15) * 32 + l4 * 8);
        #pragma unroll
        for (int m = 0; m < 4; ++m)
            #pragma unroll
            for (int n = 0; n < 4; ++n)
                acc[m][n] = __builtin_amdgcn_mfma_f32_16x16x32_bf16(af[m], bfr[n], acc[m][n], 0, 0, 0);
        __syncthreads();
    }
    #pragma unroll
    for (int m = 0; m < 4; ++m) {
        int r = row0 + wr * 64 + m * 16 + l4 * 4;
        #pragma unroll
        for (int n = 0; n < 4; ++n) {
            int c = col0 + wc * 64 + n * 16 + l15;
            float bv = bias ? bias[c] : 0.f;
            #pragma unroll
            for (int q = 0; q < 4; ++q) {
                float v = acc[m][n][q] + bv;
                if (OUT_BF16) ((u16*)Cout)[(size_t)(r + q) * ldc + c] = f2bf(v);
                else          ((float*)Cout)[(size_t)(r + q) * ldc + c] = v;
            }
        }
    }
}

// ---------------- node cross-attention (bf16): V *= sigmoid(dot(Q,K)) ----------------
__global__ __launch_bounds__(128) void node_attn_b(const u16* __restrict__ Q,
                                                   const u16* __restrict__ K,
                                                   u16* __restrict__ V)
{
    int nd = blockIdx.x;
    int t = threadIdx.x;
    size_t base = (size_t)nd * HIDD;
    float p = bf2f(Q[base + t]) * bf2f(K[base + t]);
    #pragma unroll
    for (int off = 32; off; off >>= 1) p += __shfl_down(p, off);
    __shared__ float sm[2];
    if ((t & 63) == 0) sm[t >> 6] = p;
    __syncthreads();
    float s = sm[0] + sm[1];
    float sig = 1.f / (1.f + expf(-s));
    V[base + t] = f2bf(bf2f(V[base + t]) * sig);
}

// ---------------- GAT attention-coefficient dots ----------------
__global__ __launch_bounds__(256) void att_dots1_b(const u16* __restrict__ h1,
    const float* __restrict__ asv, const float* __restrict__ adv,
    float* __restrict__ a_src, float* __restrict__ a_dst)
{
    int nd = blockIdx.x;
    int t = threadIdx.x;
    int w = t >> 6, l = t & 63;
    const u16* hr = h1 + (size_t)nd * H1D + w * HIDD;
    const float* sv = asv + w * HIDD;
    const float* dv = adv + w * HIDD;
    float h0v = bf2f(hr[l]), h1v = bf2f(hr[l + 64]);
    float ps = h0v * sv[l] + h1v * sv[l + 64];
    float pd = h0v * dv[l] + h1v * dv[l + 64];
    #pragma unroll
    for (int off = 32; off; off >>= 1) {
        ps += __shfl_down(ps, off);
        pd += __shfl_down(pd, off);
    }
    if (l == 0) { a_src[nd * NHEADS + w] = ps; a_dst[nd * NHEADS + w] = pd; }
}

__global__ __launch_bounds__(128) void att_dots2(const float* __restrict__ h2,
    const float* __restrict__ sv, const float* __restrict__ dv,
    float* __restrict__ a_src, float* __restrict__ a_dst)
{
    int nd = blockIdx.x;
    int t = threadIdx.x;
    float hv = h2[(size_t)nd * HIDD + t];
    float ps = hv * sv[t], pd = hv * dv[t];
    #pragma unroll
    for (int off = 32; off; off >>= 1) {
        ps += __shfl_down(ps, off);
        pd += __shfl_down(pd, off);
    }
    __shared__ float sm[4];
    if ((t & 63) == 0) { sm[t >> 6] = ps; sm[2 + (t >> 6)] = pd; }
    __syncthreads();
    if (t == 0) { a_src[nd] = sm[0] + sm[1]; a_dst[nd] = sm[2] + sm[3]; }
}

// ---------------- edge exp+denominator pass ----------------
template<int H>
__global__ __launch_bounds__(256) void edge_sum_k(const int* __restrict__ ei,
    const float* __restrict__ asrc, const float* __restrict__ adst,
    float* __restrict__ den, float* __restrict__ exb)
{
    int e = blockIdx.x * 256 + threadIdx.x;
    if (e >= EEDG) return;
    int s, d;
    edge_sd(ei, e, s, d);
    #pragma unroll
    for (int h = 0; h < H; ++h) {
        float a = asrc[s * H + h] + adst[d * H + h];
        a = a >= 0.f ? a : 0.2f * a;
        float ex = expf(a);
        exb[(size_t)e * H + h] = ex;
        atomicAdd(&den[d * H + h], ex);
    }
}

// ---------------- gather aggregation ----------------
// layer 1: H=4, C=512, bf16 in/out, 256 threads x 2 cols
__global__ __launch_bounds__(256) void agg1_b(const int* __restrict__ rowptr, const int* __restrict__ esrc,
    const int* __restrict__ eidx, const u16* __restrict__ h1b,
    const float* __restrict__ exb, const float* __restrict__ den,
    const float* __restrict__ bias, u16* __restrict__ o1b)
{
    int d = blockIdx.x;
    int t = threadIdx.x;
    int c0 = t * 2;
    int h = c0 >> 7;
    int beg = rowptr[d], end = rowptr[d + 1];
    float invd = 1.f / (den[d * NHEADS + h] + 1e-16f);
    float a0 = 0.f, a1 = 0.f;
    for (int i = beg; i < end; ++i) {
        int s = esrc[i];
        int e = eidx[i];
        float att = exb[(size_t)e * NHEADS + h] * invd;
        u32 pair = *(const u32*)(h1b + (size_t)s * H1D + c0);
        a0 = fmaf(bf2f((u16)pair), att, a0);
        a1 = fmaf(bf2f((u16)(pair >> 16)), att, a1);
    }
    a0 += bias[c0];
    a1 += bias[c0 + 1];
    u32 o = (u32)f2bf(a0) | ((u32)f2bf(a1) << 16);
    *(u32*)(o1b + (size_t)d * H1D + c0) = o;
}

// layer 2: H=1, C=128, f32
__global__ __launch_bounds__(128) void agg2(const int* __restrict__ rowptr, const int* __restrict__ esrc,
    const int* __restrict__ eidx, const float* __restrict__ h2,
    const float* __restrict__ exb, const float* __restrict__ den,
    const float* __restrict__ bias, float* __restrict__ o2)
{
    int d = blockIdx.x;
    int c = threadIdx.x;
    int beg = rowptr[d], end = rowptr[d + 1];
    float invd = 1.f / (den[d] + 1e-16f);
    float acc = 0.f;
    for (int i = beg; i < end; ++i) {
        int s = esrc[i];
        int e = eidx[i];
        float att = exb[e] * invd;
        acc = fmaf(h2[(size_t)s * HIDD + c], att, acc);
    }
    o2[(size_t)d * HIDD + c] = acc + bias[c];
}

// ---------------- graph norm ----------------
__global__ void colstat_b(const u16* __restrict__ x, float* __restrict__ msum,
                          float* __restrict__ vsum, int n, int rpb)
{
    int C = blockDim.x;
    int c = threadIdx.x;
    int r0 = blockIdx.x * rpb;
    int r1 = min(n, r0 + rpb);
    float s = 0.f, s2 = 0.f;
    for (int r = r0; r < r1; ++r) {
        float v = bf2f(x[(size_t)r * C + c]);
        s += v;
        s2 += v * v;
    }
    atomicAdd(&msum[c], s);
    atomicAdd(&vsum[c], s2);
}

__global__ void apply_norm_elu_b(u16* __restrict__ x, const float* __restrict__ msum,
                                 const float* __restrict__ vsum, const float* __restrict__ ms,
                                 const float* __restrict__ w, const float* __restrict__ b,
                                 int n, int rpb)
{
    int C = blockDim.x;
    int c = threadIdx.x;
    const float invn = 1.f / (float)NN;
    float mean = msum[c] * invn;
    float sub = mean * ms[c];
    float var = vsum[c] * invn - 2.f * sub * mean + sub * sub;
    float inv = rsqrtf(var + 1e-5f);
    float wc = w[c] * inv, bc = b[c];
    int r0 = blockIdx.x * rpb;
    int r1 = min(n, r0 + rpb);
    for (int r = r0; r < r1; ++r) {
        float v = (bf2f(x[(size_t)r * C + c]) - sub) * wc + bc;
        v = v > 0.f ? v : expm1f(v);
        x[(size_t)r * C + c] = f2bf(v);
    }
}

__global__ void colstat(const float* __restrict__ x, float* __restrict__ msum,
                        float* __restrict__ vsum, int n, int rpb)
{
    int C = blockDim.x;
    int c = threadIdx.x;
    int r0 = blockIdx.x * rpb;
    int r1 = min(n, r0 + rpb);
    float s = 0.f, s2 = 0.f;
    for (int r = r0; r < r1; ++r) {
        float v = x[(size_t)r * C + c];
        s += v;
        s2 += v * v;
    }
    atomicAdd(&msum[c], s);
    atomicAdd(&vsum[c], s2);
}

__global__ void apply_norm_elu(float* __restrict__ x, const float* __restrict__ msum,
                               const float* __restrict__ vsum, const float* __restrict__ ms,
                               const float* __restrict__ w, const float* __restrict__ b,
                               int n, int rpb)
{
    int C = blockDim.x;
    int c = threadIdx.x;
    const float invn = 1.f / (float)NN;
    float mean = msum[c] * invn;
    float sub = mean * ms[c];
    float var = vsum[c] * invn - 2.f * sub * mean + sub * sub;
    float inv = rsqrtf(var + 1e-5f);
    float wc = w[c] * inv, bc = b[c];
    int r0 = blockIdx.x * rpb;
    int r1 = min(n, r0 + rpb);
    for (int r = r0; r < r1; ++r) {
        float v = (x[(size_t)r * C + c] - sub) * wc + bc;
        x[(size_t)r * C + c] = v > 0.f ? v : expm1f(v);
    }
}

// ---------------- final projection (128 -> 2) ----------------
__global__ __launch_bounds__(128) void final_proj(const float* __restrict__ x,
    const float* __restrict__ Wn, const float* __restrict__ bn, float* __restrict__ out)
{
    int nd = blockIdx.x;
    int t = threadIdx.x;
    float v = x[(size_t)nd * HIDD + t];
    float p0 = v * Wn[t * 2], p1 = v * Wn[t * 2 + 1];
    #pragma unroll
    for (int off = 32; off; off >>= 1) {
        p0 += __shfl_down(p0, off);
        p1 += __shfl_down(p1, off);
    }
    __shared__ float sm[4];
    if ((t & 63) == 0) { sm[t >> 6] = p0; sm[2 + (t >> 6)] = p1; }
    __syncthreads();
    if (t == 0) {
        out[nd * 2 + 0] = sm[0] + sm[1] + bn[0];
        out[nd * 2 + 1] = sm[2] + sm[3] + bn[1];
    }
}

// ---------------- host launch ----------------
extern "C" void kernel_launch(void* const* d_in, const int* in_sizes, int n_in,
                              void* d_out, int out_size, void* d_ws, size_t ws_size,
                              hipStream_t stream)
{
    const float* x   = (const float*)d_in[0];
    const int*   ei  = (const int*)d_in[1];
    const float* Wq  = (const float*)d_in[2];
    const float* Wk  = (const float*)d_in[3];
    const float* Wv  = (const float*)d_in[4];
    const float* Wo  = (const float*)d_in[5];
    const float* bo  = (const float*)d_in[6];
    const float* W1  = (const float*)d_in[7];
    const float* as1 = (const float*)d_in[8];
    const float* ad1 = (const float*)d_in[9];
    const float* b1  = (const float*)d_in[10];
    const float* g1w = (const float*)d_in[11];
    const float* g1b = (const float*)d_in[12];
    const float* g1m = (const float*)d_in[13];
    const float* W2  = (const float*)d_in[14];
    const float* as2 = (const float*)d_in[15];
    const float* ad2 = (const float*)d_in[16];
    const float* b2  = (const float*)d_in[17];
    const float* g2w = (const float*)d_in[18];
    const float* g2b = (const float*)d_in[19];
    const float* g2m = (const float*)d_in[20];
    const float* Wn  = (const float*)d_in[21];
    const float* bn  = (const float*)d_in[22];
    float* out = (float*)d_out;

    // ---- workspace layout (bf16 region first, all 16B aligned) ----
    u16* usw = (u16*)d_ws;
    size_t uo = 0;
    u16* xb  = usw + uo; uo += (size_t)MP * 896;
    u16* h1b = usw + uo; uo += (size_t)MP * 512;
    u16* qb  = usw + uo; uo += (size_t)MP * 128;
    u16* kb  = usw + uo; uo += (size_t)MP * 128;
    u16* vb  = usw + uo; uo += (size_t)MP * 128;
    u16* o1b = usw + uo; uo += (size_t)MP * 512;
    u16* wqT = usw + uo; uo += 128 * 128;
    u16* wkT = usw + uo; uo += 128 * 768;
    u16* wvT = usw + uo; uo += 128 * 768;
    u16* woT = usw + uo; uo += 128 * 256;
    u16* w1T = usw + uo; uo += 512 * 896;
    u16* w2T = usw + uo; uo += 128 * 512;
    float* fws = (float*)(usw + uo);
    size_t fo = 0;
    float* asrc = fws + fo; fo += NN * NHEADS;
    float* adst = fws + fo; fo += NN * NHEADS;
    float* den  = fws + fo; fo += NN * NHEADS;
    float* msum = fws + fo; fo += 512;
    float* vsum = fws + fo; fo += 512;
    int* iws = (int*)(fws + fo);
    size_t io = 0;
    int* rowptr = iws + io; io += NN + 1;
    int* degcur = iws + io; io += NN;
    int* esrc   = iws + io; io += EEDG;
    int* eidx   = iws + io; io += EEDG;
    int* spart  = iws + io; io += 256;
    // reuse xb region after last xb read (h1 GEMM): exb, h2, o2
    float* exb = (float*)xb;
    float* h2  = exb + (size_t)EEDG * NHEADS;       // 2.2M floats
    float* o2  = h2 + (size_t)MP * 128;
    u16* h0b = qb;   // reuse q after node_attn

    const int EB = (EEDG + 255) / 256;

    // --- weight casts (transposed to N x K) ---
    cast_wT<<<dim3(32, 2),   256, 0, stream>>>(Wq, wqT, 128, 128);
    cast_wT<<<dim3(192, 2),  256, 0, stream>>>(Wk, wkT, 768, 128);
    cast_wT<<<dim3(192, 2),  256, 0, stream>>>(Wv, wvT, 768, 128);
    cast_wT<<<dim3(64, 2),   256, 0, stream>>>(Wo, woT, 256, 128);
    cast_wT<<<dim3(224, 8),  256, 0, stream>>>(W1, w1T, 896, 512);
    cast_wT<<<dim3(128, 2),  256, 0, stream>>>(W2, w2T, 512, 128);
    cast_pad_x<<<8192, 256, 0, stream>>>((const float4*)x, xb);

    // --- CSR build ---
    fillk_i<<<196, 256, 0, stream>>>(degcur, 0, NN);
    count_deg<<<EB, 256, 0, stream>>>(ei, degcur);
    scan_bsum<<<SCAN_NB, 256, 0, stream>>>(degcur, spart);
    scan_part<<<1, 256, 0, stream>>>(spart);
    scan_write<<<SCAN_NB, 256, 0, stream>>>(degcur, spart, rowptr);
    fillk_i<<<196, 256, 0, stream>>>(degcur, 0, NN);
    fill_csr<<<EB, 256, 0, stream>>>(ei, rowptr, degcur, esrc, eidx);

    // --- cross attention ---
    gemm_mfma<1><<<dim3(1, MT), 256, 0, stream>>>(xb, 896, 128, (const u16*)nullptr, 0, 0, wqT, qb, 128, nullptr);
    gemm_mfma<1><<<dim3(1, MT), 256, 0, stream>>>(xb + 128, 896, 768, (const u16*)nullptr, 0, 0, wkT, kb, 128, nullptr);
    gemm_mfma<1><<<dim3(1, MT), 256, 0, stream>>>(xb + 128, 896, 768, (const u16*)nullptr, 0, 0, wvT, vb, 128, nullptr);
    node_attn_b<<<NN, 128, 0, stream>>>(qb, kb, vb);

    // --- h0 = [x_struct | attn] @ Wo + bo (fused two-region A) ---
    gemm_mfma<1><<<dim3(1, MT), 256, 0, stream>>>(xb, 896, 128, vb, 128, 128, woT, h0b, 128, bo);

    // --- h1 = [h0 | x_sem] @ W1 (fused two-region A) ---
    gemm_mfma<1><<<dim3(4, MT), 256, 0, stream>>>(h0b, 128, 128, xb + 128, 896, 768, w1T, h1b, 512, nullptr);

    // --- GAT layer 1 ---
    att_dots1_b<<<NN, 256, 0, stream>>>(h1b, as1, ad1, asrc, adst);
    fillk<<<196, 256, 0, stream>>>(den, 0.f, (long)NN * NHEADS);
    edge_sum_k<NHEADS><<<EB, 256, 0, stream>>>(ei, asrc, adst, den, exb);
    agg1_b<<<NN, 256, 0, stream>>>(rowptr, esrc, eidx, h1b, exb, den, b1, o1b);

    // --- graph norm 1 + ELU (bf16 in place) ---
    fillk<<<4, 256, 0, stream>>>(msum, 0.f, 1024);
    colstat_b<<<(NN + 127) / 128, H1D, 0, stream>>>(o1b, msum, vsum, NN, 128);
    apply_norm_elu_b<<<(NN + 127) / 128, H1D, 0, stream>>>(o1b, msum, vsum, g1m, g1w, g1b, NN, 128);

    // --- GAT layer 2 ---
    gemm_mfma<0><<<dim3(1, MT), 256, 0, stream>>>(o1b, 512, 512, (const u16*)nullptr, 0, 0, w2T, h2, 128, nullptr);
    att_dots2<<<NN, 128, 0, stream>>>(h2, as2, ad2, asrc, adst);
    fillk<<<196, 256, 0, stream>>>(den, 0.f, (long)NN);
    edge_sum_k<1><<<EB, 256, 0, stream>>>(ei, asrc, adst, den, exb);
    agg2<<<NN, 128, 0, stream>>>(rowptr, esrc, eidx, h2, exb, den, b2, o2);

    // --- graph norm 2 + ELU ---
    fillk<<<4, 256, 0, stream>>>(msum, 0.f, 1024);
    colstat<<<(NN + 127) / 128, HIDD, 0, stream>>>(o2, msum, vsum, NN, 128);
    apply_norm_elu<<<(NN + 127) / 128, HIDD, 0, stream>>>(o2, msum, vsum, g2m, g2w, g2b, NN, 128);

    // --- output projection ---
    final_proj<<<NN, 128, 0, stream>>>(o2, Wn, bn, out);
}

// Round 4
// 664.089 us; speedup vs baseline: 4.5075x; 1.4316x over previous
//
#include <hip/hip_runtime.h>
#include <math.h>

#define NN 50000
#define NE 500000
#define EEDG 550000          // NE + NN self loops
#define SDIM 128             // STRUCT
#define MDIM 768             // SEM
#define HIDD 128             // HID
#define NHEADS 4
#define INDIM 896            // STRUCT + SEM
#define H1D 512              // HEADS*HID
#define SCAN_NB 196          // ceil(NN/256)
#define MP 50048             // NN padded to 128*391
#define MT 391               // row tiles of 128

typedef unsigned short u16;
typedef unsigned int u32;
typedef __attribute__((ext_vector_type(8))) short short8;
typedef __attribute__((ext_vector_type(4))) float f32x4;

// ---------------- bf16 helpers ----------------
__device__ __forceinline__ u16 f2bf(float f) {
    union { float f; u32 u; } v; v.f = f;
    u32 r = v.u + 0x7FFFu + ((v.u >> 16) & 1u);
    return (u16)(r >> 16);
}
__device__ __forceinline__ float bf2f(u16 h) {
    union { u32 u; float f; } v; v.u = ((u32)h) << 16;
    return v.f;
}

__device__ __forceinline__ void gl_lds16(const u16* g, u16* l) {
    __builtin_amdgcn_global_load_lds(
        (const __attribute__((address_space(1))) void*)g,
        (__attribute__((address_space(3))) void*)l, 16, 0, 0);
}

// ---------------- utility ----------------
__device__ __forceinline__ void edge_sd(const int* __restrict__ ei, int e, int& s, int& d) {
    if (e < NE) { s = ei[e]; d = ei[NE + e]; }
    else        { s = e - NE; d = e - NE; }
}

__global__ void fillk(float* __restrict__ p, float v, long count) {
    long i = (long)blockIdx.x * blockDim.x + threadIdx.x;
    long stride = (long)gridDim.x * blockDim.x;
    for (; i < count; i += stride) p[i] = v;
}

__global__ void fillk_i(int* __restrict__ p, int v, long count) {
    long i = (long)blockIdx.x * blockDim.x + threadIdx.x;
    long stride = (long)gridDim.x * blockDim.x;
    for (; i < count; i += stride) p[i] = v;
}

// ---------------- casts ----------------
__global__ __launch_bounds__(256) void cast_pad_x(const float4* __restrict__ x4, u16* __restrict__ xb) {
    const long total = (long)MP * 224;
    long i = (long)blockIdx.x * blockDim.x + threadIdx.x;
    long stride = (long)gridDim.x * blockDim.x;
    for (; i < total; i += stride) {
        int row = (int)(i / 224);
        int c4 = (int)(i - (long)row * 224);
        float4 v = make_float4(0.f, 0.f, 0.f, 0.f);
        if (row < NN) v = x4[(size_t)row * 224 + c4];
        short4 o;
        o.x = (short)f2bf(v.x); o.y = (short)f2bf(v.y);
        o.z = (short)f2bf(v.z); o.w = (short)f2bf(v.w);
        *(short4*)(xb + (size_t)row * 896 + c4 * 4) = o;
    }
}

// W (K x N f32, row-major) -> Wb (N x K bf16) transposed cast
__global__ __launch_bounds__(256) void cast_wT(const float* __restrict__ W, u16* __restrict__ Wb, int K, int N) {
    int k = blockIdx.x * 4 + (threadIdx.x >> 6);
    int n = blockIdx.y * 64 + (threadIdx.x & 63);
    if (k < K && n < N) Wb[(size_t)n * K + k] = f2bf(W[(size_t)k * N + n]);
}

// ---------------- CSR build ----------------
__global__ __launch_bounds__(256) void count_deg(const int* __restrict__ ei, int* __restrict__ deg) {
    int e = blockIdx.x * 256 + threadIdx.x;
    if (e >= EEDG) return;
    int d = e < NE ? ei[NE + e] : e - NE;
    atomicAdd(&deg[d], 1);
}

__global__ __launch_bounds__(256) void scan_bsum(const int* __restrict__ deg, int* __restrict__ part) {
    __shared__ int s[256];
    int t = threadIdx.x;
    int idx = blockIdx.x * 256 + t;
    s[t] = idx < NN ? deg[idx] : 0;
    __syncthreads();
    for (int off = 128; off; off >>= 1) {
        if (t < off) s[t] += s[t + off];
        __syncthreads();
    }
    if (t == 0) part[blockIdx.x] = s[0];
}

__global__ __launch_bounds__(256) void scan_part(int* __restrict__ part) {
    __shared__ int s[256];
    int t = threadIdx.x;
    int v = t < SCAN_NB ? part[t] : 0;
    s[t] = v;
    __syncthreads();
    for (int off = 1; off < 256; off <<= 1) {
        int x = t >= off ? s[t - off] : 0;
        __syncthreads();
        s[t] += x;
        __syncthreads();
    }
    if (t < SCAN_NB) part[t] = s[t] - v;   // exclusive
}

__global__ __launch_bounds__(256) void scan_write(const int* __restrict__ deg, const int* __restrict__ part,
                                                  int* __restrict__ rowptr) {
    __shared__ int s[256];
    int t = threadIdx.x;
    int idx = blockIdx.x * 256 + t;
    int v = idx < NN ? deg[idx] : 0;
    s[t] = v;
    __syncthreads();
    for (int off = 1; off < 256; off <<= 1) {
        int x = t >= off ? s[t - off] : 0;
        __syncthreads();
        s[t] += x;
        __syncthreads();
    }
    if (idx < NN) rowptr[idx] = part[blockIdx.x] + s[t] - v;
    if (idx == NN - 1) rowptr[NN] = EEDG;
}

__global__ __launch_bounds__(256) void fill_csr(const int* __restrict__ ei, const int* __restrict__ rowptr,
                                                int* __restrict__ cur, int* __restrict__ esrc) {
    int e = blockIdx.x * 256 + threadIdx.x;
    if (e >= EEDG) return;
    int s, d;
    edge_sd(ei, e, s, d);
    int p = rowptr[d] + atomicAdd(&cur[d], 1);
    esrc[p] = s;
}

// ---------------- MFMA bf16 GEMM body ----------------
// C tile [row0:+128, col0:+128] of [A1 (K1) | A2 (K2)] @ B^T  (B stored N x K bf16)
template<int OUT_BF16>
__device__ __forceinline__ void gemm_body(
    u16* __restrict__ Asm, u16* __restrict__ Bsm,
    const u16* __restrict__ A1, int lda1, int K1,
    const u16* __restrict__ A2, int lda2, int K2,
    const u16* __restrict__ Bw,
    void* __restrict__ Cout, int ldc,
    const float* __restrict__ bias, int row0, int col0)
{
    const int tid = threadIdx.x;
    const int wave = tid >> 6, lane = tid & 63;
    const int wr = wave >> 1, wc = wave & 1;
    const int K = K1 + K2;
    const int srow = tid >> 2;
    const int skp = (tid & 3) * 8;
    const int l15 = lane & 15, l4 = lane >> 4;

    f32x4 acc[4][4];
    #pragma unroll
    for (int i = 0; i < 4; ++i)
        #pragma unroll
        for (int j = 0; j < 4; ++j)
            acc[i][j] = (f32x4){0.f, 0.f, 0.f, 0.f};

    for (int k0 = 0; k0 < K; k0 += 32) {
        const u16* Ab; int la; int kk;
        if (k0 < K1) { Ab = A1; la = lda1; kk = k0; }
        else         { Ab = A2; la = lda2; kk = k0 - K1; }
        gl_lds16(Ab + (size_t)(row0 + srow) * la + kk + skp,      Asm + srow * 32 + skp);
        gl_lds16(Ab + (size_t)(row0 + srow + 64) * la + kk + skp, Asm + (srow + 64) * 32 + skp);
        gl_lds16(Bw + (size_t)(col0 + srow) * K + k0 + skp,       Bsm + srow * 32 + skp);
        gl_lds16(Bw + (size_t)(col0 + srow + 64) * K + k0 + skp,  Bsm + (srow + 64) * 32 + skp);
        __syncthreads();
        short8 af[4], bfr[4];
        #pragma unroll
        for (int m = 0; m < 4; ++m)
            af[m] = *(const short8*)(Asm + (wr * 64 + m * 16 + l15) * 32 + l4 * 8);
        #pragma unroll
        for (int n = 0; n < 4; ++n)
            bfr[n] = *(const short8*)(Bsm + (wc * 64 + n * 16 + l15) * 32 + l4 * 8);
        #pragma unroll
        for (int m = 0; m < 4; ++m)
            #pragma unroll
            for (int n = 0; n < 4; ++n)
                acc[m][n] = __builtin_amdgcn_mfma_f32_16x16x32_bf16(af[m], bfr[n], acc[m][n], 0, 0, 0);
        __syncthreads();
    }
    #pragma unroll
    for (int m = 0; m < 4; ++m) {
        int r = row0 + wr * 64 + m * 16 + l4 * 4;
        #pragma unroll
        for (int n = 0; n < 4; ++n) {
            int c = col0 + wc * 64 + n * 16 + l15;
            float bv = bias ? bias[c] : 0.f;
            #pragma unroll
            for (int q = 0; q < 4; ++q) {
                float v = acc[m][n][q] + bv;
                if (OUT_BF16) ((u16*)Cout)[(size_t)(r + q) * ldc + c] = f2bf(v);
                else          ((float*)Cout)[(size_t)(r + q) * ldc + c] = v;
            }
        }
    }
}

template<int OUT_BF16>
__global__ __launch_bounds__(256) void gemm_mfma(
    const u16* __restrict__ A1, int lda1, int K1,
    const u16* __restrict__ A2, int lda2, int K2,
    const u16* __restrict__ Bw,
    void* __restrict__ Cout, int ldc,
    const float* __restrict__ bias)
{
    __shared__ u16 Asm[128 * 32];
    __shared__ u16 Bsm[128 * 32];
    gemm_body<OUT_BF16>(Asm, Bsm, A1, lda1, K1, A2, lda2, K2, Bw, Cout, ldc, bias,
                        blockIdx.y * 128, blockIdx.x * 128);
}

// fused Q|K|V: blockIdx.x selects which product
__global__ __launch_bounds__(256) void gemm_qkv(
    const u16* __restrict__ xb,
    const u16* __restrict__ wqT, const u16* __restrict__ wkT, const u16* __restrict__ wvT,
    u16* __restrict__ qb, u16* __restrict__ kb, u16* __restrict__ vb)
{
    __shared__ u16 Asm[128 * 32];
    __shared__ u16 Bsm[128 * 32];
    const u16* A; const u16* B; int K; u16* C;
    if (blockIdx.x == 0)      { A = xb;       B = wqT; K = 128; C = qb; }
    else if (blockIdx.x == 1) { A = xb + 128; B = wkT; K = 768; C = kb; }
    else                      { A = xb + 128; B = wvT; K = 768; C = vb; }
    gemm_body<1>(Asm, Bsm, A, 896, K, (const u16*)nullptr, 0, 0, B, C, 128, nullptr,
                 blockIdx.y * 128, 0);
}

// ---------------- node cross-attention (bf16): V *= sigmoid(dot(Q,K)) ----------------
__global__ __launch_bounds__(128) void node_attn_b(const u16* __restrict__ Q,
                                                   const u16* __restrict__ K,
                                                   u16* __restrict__ V)
{
    int nd = blockIdx.x;
    int t = threadIdx.x;
    size_t base = (size_t)nd * HIDD;
    float p = bf2f(Q[base + t]) * bf2f(K[base + t]);
    #pragma unroll
    for (int off = 32; off; off >>= 1) p += __shfl_down(p, off);
    __shared__ float sm[2];
    if ((t & 63) == 0) sm[t >> 6] = p;
    __syncthreads();
    float s = sm[0] + sm[1];
    float sig = 1.f / (1.f + expf(-s));
    V[base + t] = f2bf(bf2f(V[base + t]) * sig);
}

// ---------------- GAT attention-coefficient dots ----------------
__global__ __launch_bounds__(256) void att_dots1_b(const u16* __restrict__ h1,
    const float* __restrict__ asv, const float* __restrict__ adv,
    float* __restrict__ a_src, float* __restrict__ a_dst)
{
    int nd = blockIdx.x;
    int t = threadIdx.x;
    int w = t >> 6, l = t & 63;
    const u16* hr = h1 + (size_t)nd * H1D + w * HIDD;
    const float* sv = asv + w * HIDD;
    const float* dv = adv + w * HIDD;
    float h0v = bf2f(hr[l]), h1v = bf2f(hr[l + 64]);
    float ps = h0v * sv[l] + h1v * sv[l + 64];
    float pd = h0v * dv[l] + h1v * dv[l + 64];
    #pragma unroll
    for (int off = 32; off; off >>= 1) {
        ps += __shfl_down(ps, off);
        pd += __shfl_down(pd, off);
    }
    if (l == 0) { a_src[nd * NHEADS + w] = ps; a_dst[nd * NHEADS + w] = pd; }
}

__global__ __launch_bounds__(128) void att_dots2_b(const u16* __restrict__ h2,
    const float* __restrict__ sv, const float* __restrict__ dv,
    float* __restrict__ a_src, float* __restrict__ a_dst)
{
    int nd = blockIdx.x;
    int t = threadIdx.x;
    float hv = bf2f(h2[(size_t)nd * HIDD + t]);
    float ps = hv * sv[t], pd = hv * dv[t];
    #pragma unroll
    for (int off = 32; off; off >>= 1) {
        ps += __shfl_down(ps, off);
        pd += __shfl_down(pd, off);
    }
    __shared__ float sm[4];
    if ((t & 63) == 0) { sm[t >> 6] = ps; sm[2 + (t >> 6)] = pd; }
    __syncthreads();
    if (t == 0) { a_src[nd] = sm[0] + sm[1]; a_dst[nd] = sm[2] + sm[3]; }
}

// ---------------- fused softmax + gather aggregation ----------------
// layer 1: H=4, C=512, block per dst, 256 thr x 2 cols, softmax inline
__global__ __launch_bounds__(256) void agg1_f(const int* __restrict__ rowptr, const int* __restrict__ esrc,
    const float* __restrict__ asrc, const float* __restrict__ adst,
    const u16* __restrict__ h1b, const float* __restrict__ bias, u16* __restrict__ o1b)
{
    int d = blockIdx.x;
    int t = threadIdx.x;
    int c0 = t * 2;
    int h = c0 >> 7;
    int beg = rowptr[d], end = rowptr[d + 1];
    float ad = adst[d * NHEADS + h];
    float n0 = 0.f, n1 = 0.f, den = 0.f;
    int i = beg;
    for (; i + 1 < end; i += 2) {
        int s0 = esrc[i], s1 = esrc[i + 1];
        float a0 = asrc[s0 * NHEADS + h] + ad;
        float a1 = asrc[s1 * NHEADS + h] + ad;
        a0 = a0 >= 0.f ? a0 : 0.2f * a0;
        a1 = a1 >= 0.f ? a1 : 0.2f * a1;
        float e0 = expf(a0), e1 = expf(a1);
        u32 p0 = *(const u32*)(h1b + (size_t)s0 * H1D + c0);
        u32 p1 = *(const u32*)(h1b + (size_t)s1 * H1D + c0);
        den += e0 + e1;
        n0 = fmaf(bf2f((u16)p0), e0, n0);
        n1 = fmaf(bf2f((u16)(p0 >> 16)), e0, n1);
        n0 = fmaf(bf2f((u16)p1), e1, n0);
        n1 = fmaf(bf2f((u16)(p1 >> 16)), e1, n1);
    }
    if (i < end) {
        int s0 = esrc[i];
        float a0 = asrc[s0 * NHEADS + h] + ad;
        a0 = a0 >= 0.f ? a0 : 0.2f * a0;
        float e0 = expf(a0);
        u32 p0 = *(const u32*)(h1b + (size_t)s0 * H1D + c0);
        den += e0;
        n0 = fmaf(bf2f((u16)p0), e0, n0);
        n1 = fmaf(bf2f((u16)(p0 >> 16)), e0, n1);
    }
    float invd = 1.f / (den + 1e-16f);
    float a0o = n0 * invd + bias[c0];
    float a1o = n1 * invd + bias[c0 + 1];
    u32 o = (u32)f2bf(a0o) | ((u32)f2bf(a1o) << 16);
    *(u32*)(o1b + (size_t)d * H1D + c0) = o;
}

// layer 2: H=1, C=128, wave per dst (4 dst/block), 64 lanes x 2 cols, bf16 src, f32 out
__global__ __launch_bounds__(256) void agg2_f(const int* __restrict__ rowptr, const int* __restrict__ esrc,
    const float* __restrict__ asrc, const float* __restrict__ adst,
    const u16* __restrict__ h2b, const float* __restrict__ bias, float* __restrict__ o2)
{
    int w = threadIdx.x >> 6, l = threadIdx.x & 63;
    int d = blockIdx.x * 4 + w;
    if (d >= NN) return;
    int c0 = l * 2;
    int beg = rowptr[d], end = rowptr[d + 1];
    float ad = adst[d];
    float n0 = 0.f, n1 = 0.f, den = 0.f;
    int i = beg;
    for (; i + 1 < end; i += 2) {
        int s0 = esrc[i], s1 = esrc[i + 1];
        float a0 = asrc[s0] + ad;
        float a1 = asrc[s1] + ad;
        a0 = a0 >= 0.f ? a0 : 0.2f * a0;
        a1 = a1 >= 0.f ? a1 : 0.2f * a1;
        float e0 = expf(a0), e1 = expf(a1);
        u32 p0 = *(const u32*)(h2b + (size_t)s0 * HIDD + c0);
        u32 p1 = *(const u32*)(h2b + (size_t)s1 * HIDD + c0);
        den += e0 + e1;
        n0 = fmaf(bf2f((u16)p0), e0, n0);
        n1 = fmaf(bf2f((u16)(p0 >> 16)), e0, n1);
        n0 = fmaf(bf2f((u16)p1), e1, n0);
        n1 = fmaf(bf2f((u16)(p1 >> 16)), e1, n1);
    }
    if (i < end) {
        int s0 = esrc[i];
        float a0 = asrc[s0] + ad;
        a0 = a0 >= 0.f ? a0 : 0.2f * a0;
        float e0 = expf(a0);
        u32 p0 = *(const u32*)(h2b + (size_t)s0 * HIDD + c0);
        den += e0;
        n0 = fmaf(bf2f((u16)p0), e0, n0);
        n1 = fmaf(bf2f((u16)(p0 >> 16)), e0, n1);
    }
    float invd = 1.f / (den + 1e-16f);
    o2[(size_t)d * HIDD + c0]     = n0 * invd + bias[c0];
    o2[(size_t)d * HIDD + c0 + 1] = n1 * invd + bias[c0 + 1];
}

// ---------------- graph norm ----------------
__global__ void colstat_b(const u16* __restrict__ x, float* __restrict__ msum,
                          float* __restrict__ vsum, int n, int rpb)
{
    int C = blockDim.x;
    int c = threadIdx.x;
    int r0 = blockIdx.x * rpb;
    int r1 = min(n, r0 + rpb);
    float s = 0.f, s2 = 0.f;
    for (int r = r0; r < r1; ++r) {
        float v = bf2f(x[(size_t)r * C + c]);
        s += v;
        s2 += v * v;
    }
    atomicAdd(&msum[c], s);
    atomicAdd(&vsum[c], s2);
}

__global__ void apply_norm_elu_b(u16* __restrict__ x, const float* __restrict__ msum,
                                 const float* __restrict__ vsum, const float* __restrict__ ms,
                                 const float* __restrict__ w, const float* __restrict__ b,
                                 int n, int rpb)
{
    int C = blockDim.x;
    int c = threadIdx.x;
    const float invn = 1.f / (float)NN;
    float mean = msum[c] * invn;
    float sub = mean * ms[c];
    float var = vsum[c] * invn - 2.f * sub * mean + sub * sub;
    float inv = rsqrtf(var + 1e-5f);
    float wc = w[c] * inv, bc = b[c];
    int r0 = blockIdx.x * rpb;
    int r1 = min(n, r0 + rpb);
    for (int r = r0; r < r1; ++r) {
        float v = (bf2f(x[(size_t)r * C + c]) - sub) * wc + bc;
        v = v > 0.f ? v : expm1f(v);
        x[(size_t)r * C + c] = f2bf(v);
    }
}

__global__ void colstat(const float* __restrict__ x, float* __restrict__ msum,
                        float* __restrict__ vsum, int n, int rpb)
{
    int C = blockDim.x;
    int c = threadIdx.x;
    int r0 = blockIdx.x * rpb;
    int r1 = min(n, r0 + rpb);
    float s = 0.f, s2 = 0.f;
    for (int r = r0; r < r1; ++r) {
        float v = x[(size_t)r * C + c];
        s += v;
        s2 += v * v;
    }
    atomicAdd(&msum[c], s);
    atomicAdd(&vsum[c], s2);
}

// ---------------- fused norm2 + ELU + final projection ----------------
__global__ __launch_bounds__(128) void norm2_proj(const float* __restrict__ o2,
    const float* __restrict__ msum, const float* __restrict__ vsum,
    const float* __restrict__ ms, const float* __restrict__ w, const float* __restrict__ b,
    const float* __restrict__ Wn, const float* __restrict__ bn, float* __restrict__ out)
{
    int nd = blockIdx.x;
    int t = threadIdx.x;
    const float invn = 1.f / (float)NN;
    float mean = msum[t] * invn;
    float sub = mean * ms[t];
    float var = vsum[t] * invn - 2.f * sub * mean + sub * sub;
    float inv = rsqrtf(var + 1e-5f);
    float v = (o2[(size_t)nd * HIDD + t] - sub) * w[t] * inv + b[t];
    v = v > 0.f ? v : expm1f(v);
    float p0 = v * Wn[t * 2], p1 = v * Wn[t * 2 + 1];
    #pragma unroll
    for (int off = 32; off; off >>= 1) {
        p0 += __shfl_down(p0, off);
        p1 += __shfl_down(p1, off);
    }
    __shared__ float sm[4];
    if ((t & 63) == 0) { sm[t >> 6] = p0; sm[2 + (t >> 6)] = p1; }
    __syncthreads();
    if (t == 0) {
        out[nd * 2 + 0] = sm[0] + sm[1] + bn[0];
        out[nd * 2 + 1] = sm[2] + sm[3] + bn[1];
    }
}

// ---------------- host launch ----------------
extern "C" void kernel_launch(void* const* d_in, const int* in_sizes, int n_in,
                              void* d_out, int out_size, void* d_ws, size_t ws_size,
                              hipStream_t stream)
{
    const float* x   = (const float*)d_in[0];
    const int*   ei  = (const int*)d_in[1];
    const float* Wq  = (const float*)d_in[2];
    const float* Wk  = (const float*)d_in[3];
    const float* Wv  = (const float*)d_in[4];
    const float* Wo  = (const float*)d_in[5];
    const float* bo  = (const float*)d_in[6];
    const float* W1  = (const float*)d_in[7];
    const float* as1 = (const float*)d_in[8];
    const float* ad1 = (const float*)d_in[9];
    const float* b1  = (const float*)d_in[10];
    const float* g1w = (const float*)d_in[11];
    const float* g1b = (const float*)d_in[12];
    const float* g1m = (const float*)d_in[13];
    const float* W2  = (const float*)d_in[14];
    const float* as2 = (const float*)d_in[15];
    const float* ad2 = (const float*)d_in[16];
    const float* b2  = (const float*)d_in[17];
    const float* g2w = (const float*)d_in[18];
    const float* g2b = (const float*)d_in[19];
    const float* g2m = (const float*)d_in[20];
    const float* Wn  = (const float*)d_in[21];
    const float* bn  = (const float*)d_in[22];
    float* out = (float*)d_out;

    // ---- workspace layout ----
    u16* usw = (u16*)d_ws;
    size_t uo = 0;
    u16* xb  = usw + uo; uo += (size_t)MP * 896;
    u16* h1b = usw + uo; uo += (size_t)MP * 512;
    u16* qb  = usw + uo; uo += (size_t)MP * 128;
    u16* kb  = usw + uo; uo += (size_t)MP * 128;   // later h2b
    u16* vb  = usw + uo; uo += (size_t)MP * 128;
    u16* o1b = usw + uo; uo += (size_t)MP * 512;
    u16* wqT = usw + uo; uo += 128 * 128;
    u16* wkT = usw + uo; uo += 128 * 768;
    u16* wvT = usw + uo; uo += 128 * 768;
    u16* woT = usw + uo; uo += 128 * 256;
    u16* w1T = usw + uo; uo += 512 * 896;
    u16* w2T = usw + uo; uo += 128 * 512;
    float* fws = (float*)(usw + uo);
    size_t fo = 0;
    float* asrc = fws + fo; fo += NN * NHEADS;
    float* adst = fws + fo; fo += NN * NHEADS;
    float* msum = fws + fo; fo += 512;
    float* vsum = fws + fo; fo += 512;
    int* iws = (int*)(fws + fo);
    size_t io = 0;
    int* rowptr = iws + io; io += NN + 1;
    int* degcur = iws + io; io += NN;
    int* esrc   = iws + io; io += EEDG;
    int* spart  = iws + io; io += 256;
    // aliases: xb region free after h1 GEMM
    float* o2  = (float*)xb;
    u16* h0b = qb;   // reuse q after node_attn
    u16* h2b = kb;   // reuse k after node_attn

    const int EB = (EEDG + 255) / 256;

    // --- weight casts (transposed to N x K) ---
    cast_wT<<<dim3(32, 2),   256, 0, stream>>>(Wq, wqT, 128, 128);
    cast_wT<<<dim3(192, 2),  256, 0, stream>>>(Wk, wkT, 768, 128);
    cast_wT<<<dim3(192, 2),  256, 0, stream>>>(Wv, wvT, 768, 128);
    cast_wT<<<dim3(64, 2),   256, 0, stream>>>(Wo, woT, 256, 128);
    cast_wT<<<dim3(224, 8),  256, 0, stream>>>(W1, w1T, 896, 512);
    cast_wT<<<dim3(128, 2),  256, 0, stream>>>(W2, w2T, 512, 128);
    cast_pad_x<<<8192, 256, 0, stream>>>((const float4*)x, xb);

    // --- CSR build (esrc only) ---
    fillk_i<<<196, 256, 0, stream>>>(degcur, 0, NN);
    count_deg<<<EB, 256, 0, stream>>>(ei, degcur);
    scan_bsum<<<SCAN_NB, 256, 0, stream>>>(degcur, spart);
    scan_part<<<1, 256, 0, stream>>>(spart);
    scan_write<<<SCAN_NB, 256, 0, stream>>>(degcur, spart, rowptr);
    fillk_i<<<196, 256, 0, stream>>>(degcur, 0, NN);
    fill_csr<<<EB, 256, 0, stream>>>(ei, rowptr, degcur, esrc);

    // --- cross attention: Q|K|V in one dispatch, then gate ---
    gemm_qkv<<<dim3(3, MT), 256, 0, stream>>>(xb, wqT, wkT, wvT, qb, kb, vb);
    node_attn_b<<<NN, 128, 0, stream>>>(qb, kb, vb);

    // --- h0 = [x_struct | attn] @ Wo + bo (fused two-region A) ---
    gemm_mfma<1><<<dim3(1, MT), 256, 0, stream>>>(xb, 896, 128, vb, 128, 128, woT, h0b, 128, bo);

    // --- h1 = [h0 | x_sem] @ W1 (fused two-region A) ---
    gemm_mfma<1><<<dim3(4, MT), 256, 0, stream>>>(h0b, 128, 128, xb + 128, 896, 768, w1T, h1b, 512, nullptr);

    // --- GAT layer 1 (fused softmax + gather) ---
    att_dots1_b<<<NN, 256, 0, stream>>>(h1b, as1, ad1, asrc, adst);
    agg1_f<<<NN, 256, 0, stream>>>(rowptr, esrc, asrc, adst, h1b, b1, o1b);

    // --- graph norm 1 + ELU (bf16 in place) ---
    fillk<<<4, 256, 0, stream>>>(msum, 0.f, 1024);
    colstat_b<<<(NN + 127) / 128, H1D, 0, stream>>>(o1b, msum, vsum, NN, 128);
    apply_norm_elu_b<<<(NN + 127) / 128, H1D, 0, stream>>>(o1b, msum, vsum, g1m, g1w, g1b, NN, 128);

    // --- GAT layer 2 ---
    gemm_mfma<1><<<dim3(1, MT), 256, 0, stream>>>(o1b, 512, 512, (const u16*)nullptr, 0, 0, w2T, h2b, 128, nullptr);
    att_dots2_b<<<NN, 128, 0, stream>>>(h2b, as2, ad2, asrc, adst);
    agg2_f<<<(NN + 3) / 4, 256, 0, stream>>>(rowptr, esrc, asrc, adst, h2b, b2, o2);

    // --- graph norm 2 + ELU + projection (fused) ---
    fillk<<<4, 256, 0, stream>>>(msum, 0.f, 1024);
    colstat<<<(NN + 127) / 128, HIDD, 0, stream>>>(o2, msum, vsum, NN, 128);
    norm2_proj<<<NN, 128, 0, stream>>>(o2, msum, vsum, g2m, g2w, g2b, Wn, bn, out);
}

// Round 5
// 648.973 us; speedup vs baseline: 4.6125x; 1.0233x over previous
//
#include <hip/hip_runtime.h>
#include <math.h>

#define NN 50000
#define NE 500000
#define EEDG 550000          // NE + NN self loops
#define SDIM 128             // STRUCT
#define MDIM 768             // SEM
#define HIDD 128             // HID
#define NHEADS 4
#define INDIM 896            // STRUCT + SEM
#define H1D 512              // HEADS*HID
#define SCAN_NB 196          // ceil(NN/256)
#define MP 50048             // NN padded to 128*391
#define MT 391               // row tiles of 128

typedef unsigned short u16;
typedef unsigned int u32;
typedef __attribute__((ext_vector_type(8))) short short8;
typedef __attribute__((ext_vector_type(4))) float f32x4;

// ---------------- bf16 helpers ----------------
__device__ __forceinline__ u16 f2bf(float f) {
    union { float f; u32 u; } v; v.f = f;
    u32 r = v.u + 0x7FFFu + ((v.u >> 16) & 1u);
    return (u16)(r >> 16);
}
__device__ __forceinline__ float bf2f(u16 h) {
    union { u32 u; float f; } v; v.u = ((u32)h) << 16;
    return v.f;
}

__device__ __forceinline__ void gl_lds16(const u16* g, u16* l) {
    __builtin_amdgcn_global_load_lds(
        (const __attribute__((address_space(1))) void*)g,
        (__attribute__((address_space(3))) void*)l, 16, 0, 0);
}

// ---------------- utility ----------------
__device__ __forceinline__ void edge_sd(const int* __restrict__ ei, int e, int& s, int& d) {
    if (e < NE) { s = ei[e]; d = ei[NE + e]; }
    else        { s = e - NE; d = e - NE; }
}

__global__ void fillk(float* __restrict__ p, float v, long count) {
    long i = (long)blockIdx.x * blockDim.x + threadIdx.x;
    long stride = (long)gridDim.x * blockDim.x;
    for (; i < count; i += stride) p[i] = v;
}

__global__ void fillk_i(int* __restrict__ p, int v, long count) {
    long i = (long)blockIdx.x * blockDim.x + threadIdx.x;
    long stride = (long)gridDim.x * blockDim.x;
    for (; i < count; i += stride) p[i] = v;
}

// ---------------- casts ----------------
__global__ __launch_bounds__(256) void cast_pad_x(const float4* __restrict__ x4, u16* __restrict__ xb) {
    const long total = (long)MP * 224;
    long i = (long)blockIdx.x * blockDim.x + threadIdx.x;
    long stride = (long)gridDim.x * blockDim.x;
    for (; i < total; i += stride) {
        int row = (int)(i / 224);
        int c4 = (int)(i - (long)row * 224);
        float4 v = make_float4(0.f, 0.f, 0.f, 0.f);
        if (row < NN) v = x4[(size_t)row * 224 + c4];
        short4 o;
        o.x = (short)f2bf(v.x); o.y = (short)f2bf(v.y);
        o.z = (short)f2bf(v.z); o.w = (short)f2bf(v.w);
        *(short4*)(xb + (size_t)row * 896 + c4 * 4) = o;
    }
}

// W (K x N f32, row-major) -> Wb (N x K bf16) transposed cast
__global__ __launch_bounds__(256) void cast_wT(const float* __restrict__ W, u16* __restrict__ Wb, int K, int N) {
    int k = blockIdx.x * 4 + (threadIdx.x >> 6);
    int n = blockIdx.y * 64 + (threadIdx.x & 63);
    if (k < K && n < N) Wb[(size_t)n * K + k] = f2bf(W[(size_t)k * N + n]);
}

// ---------------- CSR build ----------------
__global__ __launch_bounds__(256) void count_deg(const int* __restrict__ ei, int* __restrict__ deg) {
    int e = blockIdx.x * 256 + threadIdx.x;
    if (e >= EEDG) return;
    int d = e < NE ? ei[NE + e] : e - NE;
    atomicAdd(&deg[d], 1);
}

__global__ __launch_bounds__(256) void scan_bsum(const int* __restrict__ deg, int* __restrict__ part) {
    __shared__ int s[256];
    int t = threadIdx.x;
    int idx = blockIdx.x * 256 + t;
    s[t] = idx < NN ? deg[idx] : 0;
    __syncthreads();
    for (int off = 128; off; off >>= 1) {
        if (t < off) s[t] += s[t + off];
        __syncthreads();
    }
    if (t == 0) part[blockIdx.x] = s[0];
}

__global__ __launch_bounds__(256) void scan_part(int* __restrict__ part) {
    __shared__ int s[256];
    int t = threadIdx.x;
    int v = t < SCAN_NB ? part[t] : 0;
    s[t] = v;
    __syncthreads();
    for (int off = 1; off < 256; off <<= 1) {
        int x = t >= off ? s[t - off] : 0;
        __syncthreads();
        s[t] += x;
        __syncthreads();
    }
    if (t < SCAN_NB) part[t] = s[t] - v;   // exclusive
}

__global__ __launch_bounds__(256) void scan_write(const int* __restrict__ deg, const int* __restrict__ part,
                                                  int* __restrict__ rowptr) {
    __shared__ int s[256];
    int t = threadIdx.x;
    int idx = blockIdx.x * 256 + t;
    int v = idx < NN ? deg[idx] : 0;
    s[t] = v;
    __syncthreads();
    for (int off = 1; off < 256; off <<= 1) {
        int x = t >= off ? s[t - off] : 0;
        __syncthreads();
        s[t] += x;
        __syncthreads();
    }
    if (idx < NN) rowptr[idx] = part[blockIdx.x] + s[t] - v;
    if (idx == NN - 1) rowptr[NN] = EEDG;
}

__global__ __launch_bounds__(256) void fill_csr(const int* __restrict__ ei, const int* __restrict__ rowptr,
                                                int* __restrict__ cur, int* __restrict__ esrc) {
    int e = blockIdx.x * 256 + threadIdx.x;
    if (e >= EEDG) return;
    int s, d;
    edge_sd(ei, e, s, d);
    int p = rowptr[d] + atomicAdd(&cur[d], 1);
    esrc[p] = s;
}

// ---------------- MFMA bf16 GEMM body ----------------
template<int OUT_BF16>
__device__ __forceinline__ void gemm_body(
    u16* __restrict__ Asm, u16* __restrict__ Bsm,
    const u16* __restrict__ A1, int lda1, int K1,
    const u16* __restrict__ A2, int lda2, int K2,
    const u16* __restrict__ Bw,
    void* __restrict__ Cout, int ldc,
    const float* __restrict__ bias, int row0, int col0)
{
    const int tid = threadIdx.x;
    const int wave = tid >> 6, lane = tid & 63;
    const int wr = wave >> 1, wc = wave & 1;
    const int K = K1 + K2;
    const int srow = tid >> 2;
    const int skp = (tid & 3) * 8;
    const int l15 = lane & 15, l4 = lane >> 4;

    f32x4 acc[4][4];
    #pragma unroll
    for (int i = 0; i < 4; ++i)
        #pragma unroll
        for (int j = 0; j < 4; ++j)
            acc[i][j] = (f32x4){0.f, 0.f, 0.f, 0.f};

    for (int k0 = 0; k0 < K; k0 += 32) {
        const u16* Ab; int la; int kk;
        if (k0 < K1) { Ab = A1; la = lda1; kk = k0; }
        else         { Ab = A2; la = lda2; kk = k0 - K1; }
        gl_lds16(Ab + (size_t)(row0 + srow) * la + kk + skp,      Asm + srow * 32 + skp);
        gl_lds16(Ab + (size_t)(row0 + srow + 64) * la + kk + skp, Asm + (srow + 64) * 32 + skp);
        gl_lds16(Bw + (size_t)(col0 + srow) * K + k0 + skp,       Bsm + srow * 32 + skp);
        gl_lds16(Bw + (size_t)(col0 + srow + 64) * K + k0 + skp,  Bsm + (srow + 64) * 32 + skp);
        __syncthreads();
        short8 af[4], bfr[4];
        #pragma unroll
        for (int m = 0; m < 4; ++m)
            af[m] = *(const short8*)(Asm + (wr * 64 + m * 16 + l15) * 32 + l4 * 8);
        #pragma unroll
        for (int n = 0; n < 4; ++n)
            bfr[n] = *(const short8*)(Bsm + (wc * 64 + n * 16 + l15) * 32 + l4 * 8);
        #pragma unroll
        for (int m = 0; m < 4; ++m)
            #pragma unroll
            for (int n = 0; n < 4; ++n)
                acc[m][n] = __builtin_amdgcn_mfma_f32_16x16x32_bf16(af[m], bfr[n], acc[m][n], 0, 0, 0);
        __syncthreads();
    }
    #pragma unroll
    for (int m = 0; m < 4; ++m) {
        int r = row0 + wr * 64 + m * 16 + l4 * 4;
        #pragma unroll
        for (int n = 0; n < 4; ++n) {
            int c = col0 + wc * 64 + n * 16 + l15;
            float bv = bias ? bias[c] : 0.f;
            #pragma unroll
            for (int q = 0; q < 4; ++q) {
                float v = acc[m][n][q] + bv;
                if (OUT_BF16) ((u16*)Cout)[(size_t)(r + q) * ldc + c] = f2bf(v);
                else          ((float*)Cout)[(size_t)(r + q) * ldc + c] = v;
            }
        }
    }
}

template<int OUT_BF16>
__global__ __launch_bounds__(256) void gemm_mfma(
    const u16* __restrict__ A1, int lda1, int K1,
    const u16* __restrict__ A2, int lda2, int K2,
    const u16* __restrict__ Bw,
    void* __restrict__ Cout, int ldc,
    const float* __restrict__ bias)
{
    __shared__ u16 Asm[128 * 32];
    __shared__ u16 Bsm[128 * 32];
    gemm_body<OUT_BF16>(Asm, Bsm, A1, lda1, K1, A2, lda2, K2, Bw, Cout, ldc, bias,
                        blockIdx.y * 128, blockIdx.x * 128);
}

// fused Q|K|V: blockIdx.x selects which product
__global__ __launch_bounds__(256) void gemm_qkv(
    const u16* __restrict__ xb,
    const u16* __restrict__ wqT, const u16* __restrict__ wkT, const u16* __restrict__ wvT,
    u16* __restrict__ qb, u16* __restrict__ kb, u16* __restrict__ vb)
{
    __shared__ u16 Asm[128 * 32];
    __shared__ u16 Bsm[128 * 32];
    const u16* A; const u16* B; int K; u16* C;
    if (blockIdx.x == 0)      { A = xb;       B = wqT; K = 128; C = qb; }
    else if (blockIdx.x == 1) { A = xb + 128; B = wkT; K = 768; C = kb; }
    else                      { A = xb + 128; B = wvT; K = 768; C = vb; }
    gemm_body<1>(Asm, Bsm, A, 896, K, (const u16*)nullptr, 0, 0, B, C, 128, nullptr,
                 blockIdx.y * 128, 0);
}

// ---------------- node cross-attention (bf16): V *= sigmoid(dot(Q,K)) ----------------
__global__ __launch_bounds__(128) void node_attn_b(const u16* __restrict__ Q,
                                                   const u16* __restrict__ K,
                                                   u16* __restrict__ V)
{
    int nd = blockIdx.x;
    int t = threadIdx.x;
    size_t base = (size_t)nd * HIDD;
    float p = bf2f(Q[base + t]) * bf2f(K[base + t]);
    #pragma unroll
    for (int off = 32; off; off >>= 1) p += __shfl_down(p, off);
    __shared__ float sm[2];
    if ((t & 63) == 0) sm[t >> 6] = p;
    __syncthreads();
    float s = sm[0] + sm[1];
    float sig = 1.f / (1.f + expf(-s));
    V[base + t] = f2bf(bf2f(V[base + t]) * sig);
}

// ---------------- GAT attention-coefficient dots ----------------
__global__ __launch_bounds__(256) void att_dots1_b(const u16* __restrict__ h1,
    const float* __restrict__ asv, const float* __restrict__ adv,
    float* __restrict__ a_src, float* __restrict__ a_dst)
{
    int nd = blockIdx.x;
    int t = threadIdx.x;
    int w = t >> 6, l = t & 63;
    const u16* hr = h1 + (size_t)nd * H1D + w * HIDD;
    const float* sv = asv + w * HIDD;
    const float* dv = adv + w * HIDD;
    float h0v = bf2f(hr[l]), h1v = bf2f(hr[l + 64]);
    float ps = h0v * sv[l] + h1v * sv[l + 64];
    float pd = h0v * dv[l] + h1v * dv[l + 64];
    #pragma unroll
    for (int off = 32; off; off >>= 1) {
        ps += __shfl_down(ps, off);
        pd += __shfl_down(pd, off);
    }
    if (l == 0) { a_src[nd * NHEADS + w] = ps; a_dst[nd * NHEADS + w] = pd; }
}

__global__ __launch_bounds__(128) void att_dots2_b(const u16* __restrict__ h2,
    const float* __restrict__ sv, const float* __restrict__ dv,
    float* __restrict__ a_src, float* __restrict__ a_dst)
{
    int nd = blockIdx.x;
    int t = threadIdx.x;
    float hv = bf2f(h2[(size_t)nd * HIDD + t]);
    float ps = hv * sv[t], pd = hv * dv[t];
    #pragma unroll
    for (int off = 32; off; off >>= 1) {
        ps += __shfl_down(ps, off);
        pd += __shfl_down(pd, off);
    }
    __shared__ float sm[4];
    if ((t & 63) == 0) { sm[t >> 6] = ps; sm[2 + (t >> 6)] = pd; }
    __syncthreads();
    if (t == 0) { a_src[nd] = sm[0] + sm[1]; a_dst[nd] = sm[2] + sm[3]; }
}

// ---------------- fused softmax + gather aggregation ----------------
// layer 1: block per dst, chunks of 64 edges; per-edge softmax computed ONCE
// (thread t handles edge t>>2, head t&3), consumed via LDS broadcast.
__global__ __launch_bounds__(256) void agg1_f(const int* __restrict__ rowptr, const int* __restrict__ esrc,
    const float* __restrict__ asrc, const float* __restrict__ adst,
    const u16* __restrict__ h1b, const float* __restrict__ bias, u16* __restrict__ o1b)
{
    __shared__ int   s_src[64];
    __shared__ float s_att[64 * NHEADS];
    int d = blockIdx.x;
    int t = threadIdx.x;
    int c0 = t * 2;
    int h = t >> 6;               // head for this thread's output columns
    int eh = t & 3;               // head this thread computes exp for
    int ee = t >> 2;              // edge slot this thread computes exp for
    int beg = rowptr[d], end = rowptr[d + 1];
    float ad_eh = adst[d * NHEADS + eh];
    float n0 = 0.f, n1 = 0.f, den = 0.f;
    for (int i0 = beg; i0 < end; i0 += 64) {
        int m = min(64, end - i0);
        float ex = 0.f; int s = 0;
        if (ee < m) {
            s = esrc[i0 + ee];    // 4 threads read same addr -> L1 broadcast
            float a = asrc[s * NHEADS + eh] + ad_eh;
            a = a >= 0.f ? a : 0.2f * a;
            ex = expf(a);
        }
        s_att[ee * NHEADS + eh] = ex;
        if (eh == 0) s_src[ee] = s;
        __syncthreads();
        int j = 0;
        for (; j + 1 < m; j += 2) {
            int sA = s_src[j], sB = s_src[j + 1];
            float aA = s_att[j * NHEADS + h], aB = s_att[(j + 1) * NHEADS + h];
            u32 pA = *(const u32*)(h1b + (size_t)sA * H1D + c0);
            u32 pB = *(const u32*)(h1b + (size_t)sB * H1D + c0);
            den += aA + aB;
            n0 = fmaf(bf2f((u16)pA), aA, n0);
            n1 = fmaf(bf2f((u16)(pA >> 16)), aA, n1);
            n0 = fmaf(bf2f((u16)pB), aB, n0);
            n1 = fmaf(bf2f((u16)(pB >> 16)), aB, n1);
        }
        if (j < m) {
            int sA = s_src[j];
            float aA = s_att[j * NHEADS + h];
            u32 pA = *(const u32*)(h1b + (size_t)sA * H1D + c0);
            den += aA;
            n0 = fmaf(bf2f((u16)pA), aA, n0);
            n1 = fmaf(bf2f((u16)(pA >> 16)), aA, n1);
        }
        __syncthreads();
    }
    float invd = 1.f / (den + 1e-16f);
    float a0o = n0 * invd + bias[c0];
    float a1o = n1 * invd + bias[c0 + 1];
    u32 o = (u32)f2bf(a0o) | ((u32)f2bf(a1o) << 16);
    *(u32*)(o1b + (size_t)d * H1D + c0) = o;
}

// layer 2: wave per dst (4/block), per-edge softmax computed once per lane,
// consumed via __shfl broadcast (no block barriers -> divergent waves OK).
__global__ __launch_bounds__(256) void agg2_f(const int* __restrict__ rowptr, const int* __restrict__ esrc,
    const float* __restrict__ asrc, const float* __restrict__ adst,
    const u16* __restrict__ h2b, const float* __restrict__ bias, float* __restrict__ o2)
{
    int w = threadIdx.x >> 6, l = threadIdx.x & 63;
    int d = blockIdx.x * 4 + w;
    if (d >= NN) return;
    int c0 = l * 2;
    int beg = rowptr[d], end = rowptr[d + 1];
    float ad = adst[d];
    float n0 = 0.f, n1 = 0.f, den = 0.f;
    for (int i0 = beg; i0 < end; i0 += 64) {
        int m = min(64, end - i0);
        float ex = 0.f; int s = 0;
        if (l < m) {
            s = esrc[i0 + l];
            float a = asrc[s] + ad;
            a = a >= 0.f ? a : 0.2f * a;
            ex = expf(a);
        }
        int j = 0;
        for (; j + 1 < m; j += 2) {
            int sA = __shfl(s, j), sB = __shfl(s, j + 1);
            float aA = __shfl(ex, j), aB = __shfl(ex, j + 1);
            u32 pA = *(const u32*)(h2b + (size_t)sA * HIDD + c0);
            u32 pB = *(const u32*)(h2b + (size_t)sB * HIDD + c0);
            den += aA + aB;
            n0 = fmaf(bf2f((u16)pA), aA, n0);
            n1 = fmaf(bf2f((u16)(pA >> 16)), aA, n1);
            n0 = fmaf(bf2f((u16)pB), aB, n0);
            n1 = fmaf(bf2f((u16)(pB >> 16)), aB, n1);
        }
        if (j < m) {
            int sA = __shfl(s, j);
            float aA = __shfl(ex, j);
            u32 pA = *(const u32*)(h2b + (size_t)sA * HIDD + c0);
            den += aA;
            n0 = fmaf(bf2f((u16)pA), aA, n0);
            n1 = fmaf(bf2f((u16)(pA >> 16)), aA, n1);
        }
    }
    float invd = 1.f / (den + 1e-16f);
    o2[(size_t)d * HIDD + c0]     = n0 * invd + bias[c0];
    o2[(size_t)d * HIDD + c0 + 1] = n1 * invd + bias[c0 + 1];
}

// ---------------- graph norm ----------------
__global__ void colstat_b(const u16* __restrict__ x, float* __restrict__ msum,
                          float* __restrict__ vsum, int n, int rpb)
{
    int C = blockDim.x;
    int c = threadIdx.x;
    int r0 = blockIdx.x * rpb;
    int r1 = min(n, r0 + rpb);
    float s = 0.f, s2 = 0.f;
    for (int r = r0; r < r1; ++r) {
        float v = bf2f(x[(size_t)r * C + c]);
        s += v;
        s2 += v * v;
    }
    atomicAdd(&msum[c], s);
    atomicAdd(&vsum[c], s2);
}

__global__ void apply_norm_elu_b(u16* __restrict__ x, const float* __restrict__ msum,
                                 const float* __restrict__ vsum, const float* __restrict__ ms,
                                 const float* __restrict__ w, const float* __restrict__ b,
                                 int n, int rpb)
{
    int C = blockDim.x;
    int c = threadIdx.x;
    const float invn = 1.f / (float)NN;
    float mean = msum[c] * invn;
    float sub = mean * ms[c];
    float var = vsum[c] * invn - 2.f * sub * mean + sub * sub;
    float inv = rsqrtf(var + 1e-5f);
    float wc = w[c] * inv, bc = b[c];
    int r0 = blockIdx.x * rpb;
    int r1 = min(n, r0 + rpb);
    for (int r = r0; r < r1; ++r) {
        float v = (bf2f(x[(size_t)r * C + c]) - sub) * wc + bc;
        v = v > 0.f ? v : expm1f(v);
        x[(size_t)r * C + c] = f2bf(v);
    }
}

__global__ void colstat(const float* __restrict__ x, float* __restrict__ msum,
                        float* __restrict__ vsum, int n, int rpb)
{
    int C = blockDim.x;
    int c = threadIdx.x;
    int r0 = blockIdx.x * rpb;
    int r1 = min(n, r0 + rpb);
    float s = 0.f, s2 = 0.f;
    for (int r = r0; r < r1; ++r) {
        float v = x[(size_t)r * C + c];
        s += v;
        s2 += v * v;
    }
    atomicAdd(&msum[c], s);
    atomicAdd(&vsum[c], s2);
}

// ---------------- fused norm2 + ELU + final projection ----------------
__global__ __launch_bounds__(128) void norm2_proj(const float* __restrict__ o2,
    const float* __restrict__ msum, const float* __restrict__ vsum,
    const float* __restrict__ ms, const float* __restrict__ w, const float* __restrict__ b,
    const float* __restrict__ Wn, const float* __restrict__ bn, float* __restrict__ out)
{
    int nd = blockIdx.x;
    int t = threadIdx.x;
    const float invn = 1.f / (float)NN;
    float mean = msum[t] * invn;
    float sub = mean * ms[t];
    float var = vsum[t] * invn - 2.f * sub * mean + sub * sub;
    float inv = rsqrtf(var + 1e-5f);
    float v = (o2[(size_t)nd * HIDD + t] - sub) * w[t] * inv + b[t];
    v = v > 0.f ? v : expm1f(v);
    float p0 = v * Wn[t * 2], p1 = v * Wn[t * 2 + 1];
    #pragma unroll
    for (int off = 32; off; off >>= 1) {
        p0 += __shfl_down(p0, off);
        p1 += __shfl_down(p1, off);
    }
    __shared__ float sm[4];
    if ((t & 63) == 0) { sm[t >> 6] = p0; sm[2 + (t >> 6)] = p1; }
    __syncthreads();
    if (t == 0) {
        out[nd * 2 + 0] = sm[0] + sm[1] + bn[0];
        out[nd * 2 + 1] = sm[2] + sm[3] + bn[1];
    }
}

// ---------------- host launch ----------------
extern "C" void kernel_launch(void* const* d_in, const int* in_sizes, int n_in,
                              void* d_out, int out_size, void* d_ws, size_t ws_size,
                              hipStream_t stream)
{
    const float* x   = (const float*)d_in[0];
    const int*   ei  = (const int*)d_in[1];
    const float* Wq  = (const float*)d_in[2];
    const float* Wk  = (const float*)d_in[3];
    const float* Wv  = (const float*)d_in[4];
    const float* Wo  = (const float*)d_in[5];
    const float* bo  = (const float*)d_in[6];
    const float* W1  = (const float*)d_in[7];
    const float* as1 = (const float*)d_in[8];
    const float* ad1 = (const float*)d_in[9];
    const float* b1  = (const float*)d_in[10];
    const float* g1w = (const float*)d_in[11];
    const float* g1b = (const float*)d_in[12];
    const float* g1m = (const float*)d_in[13];
    const float* W2  = (const float*)d_in[14];
    const float* as2 = (const float*)d_in[15];
    const float* ad2 = (const float*)d_in[16];
    const float* b2  = (const float*)d_in[17];
    const float* g2w = (const float*)d_in[18];
    const float* g2b = (const float*)d_in[19];
    const float* g2m = (const float*)d_in[20];
    const float* Wn  = (const float*)d_in[21];
    const float* bn  = (const float*)d_in[22];
    float* out = (float*)d_out;

    // ---- workspace layout ----
    u16* usw = (u16*)d_ws;
    size_t uo = 0;
    u16* xb  = usw + uo; uo += (size_t)MP * 896;
    u16* h1b = usw + uo; uo += (size_t)MP * 512;
    u16* qb  = usw + uo; uo += (size_t)MP * 128;
    u16* kb  = usw + uo; uo += (size_t)MP * 128;   // later h2b
    u16* vb  = usw + uo; uo += (size_t)MP * 128;
    u16* o1b = usw + uo; uo += (size_t)MP * 512;
    u16* wqT = usw + uo; uo += 128 * 128;
    u16* wkT = usw + uo; uo += 128 * 768;
    u16* wvT = usw + uo; uo += 128 * 768;
    u16* woT = usw + uo; uo += 128 * 256;
    u16* w1T = usw + uo; uo += 512 * 896;
    u16* w2T = usw + uo; uo += 128 * 512;
    float* fws = (float*)(usw + uo);
    size_t fo = 0;
    float* asrc = fws + fo; fo += NN * NHEADS;
    float* adst = fws + fo; fo += NN * NHEADS;
    float* msum = fws + fo; fo += 512;
    float* vsum = fws + fo; fo += 512;
    int* iws = (int*)(fws + fo);
    size_t io = 0;
    int* rowptr = iws + io; io += NN + 1;
    int* degcur = iws + io; io += NN;
    int* esrc   = iws + io; io += EEDG;
    int* spart  = iws + io; io += 256;
    // aliases: xb region free after h1 GEMM
    float* o2  = (float*)xb;
    u16* h0b = qb;   // reuse q after node_attn
    u16* h2b = kb;   // reuse k after node_attn

    const int EB = (EEDG + 255) / 256;

    // --- weight casts (transposed to N x K) ---
    cast_wT<<<dim3(32, 2),   256, 0, stream>>>(Wq, wqT, 128, 128);
    cast_wT<<<dim3(192, 2),  256, 0, stream>>>(Wk, wkT, 768, 128);
    cast_wT<<<dim3(192, 2),  256, 0, stream>>>(Wv, wvT, 768, 128);
    cast_wT<<<dim3(64, 2),   256, 0, stream>>>(Wo, woT, 256, 128);
    cast_wT<<<dim3(224, 8),  256, 0, stream>>>(W1, w1T, 896, 512);
    cast_wT<<<dim3(128, 2),  256, 0, stream>>>(W2, w2T, 512, 128);
    cast_pad_x<<<8192, 256, 0, stream>>>((const float4*)x, xb);

    // --- CSR build (esrc only) ---
    fillk_i<<<196, 256, 0, stream>>>(degcur, 0, NN);
    count_deg<<<EB, 256, 0, stream>>>(ei, degcur);
    scan_bsum<<<SCAN_NB, 256, 0, stream>>>(degcur, spart);
    scan_part<<<1, 256, 0, stream>>>(spart);
    scan_write<<<SCAN_NB, 256, 0, stream>>>(degcur, spart, rowptr);
    fillk_i<<<196, 256, 0, stream>>>(degcur, 0, NN);
    fill_csr<<<EB, 256, 0, stream>>>(ei, rowptr, degcur, esrc);

    // --- cross attention: Q|K|V in one dispatch, then gate ---
    gemm_qkv<<<dim3(3, MT), 256, 0, stream>>>(xb, wqT, wkT, wvT, qb, kb, vb);
    node_attn_b<<<NN, 128, 0, stream>>>(qb, kb, vb);

    // --- h0 = [x_struct | attn] @ Wo + bo (fused two-region A) ---
    gemm_mfma<1><<<dim3(1, MT), 256, 0, stream>>>(xb, 896, 128, vb, 128, 128, woT, h0b, 128, bo);

    // --- h1 = [h0 | x_sem] @ W1 (fused two-region A) ---
    gemm_mfma<1><<<dim3(4, MT), 256, 0, stream>>>(h0b, 128, 128, xb + 128, 896, 768, w1T, h1b, 512, nullptr);

    // --- GAT layer 1 (fused softmax + gather, cooperative exp) ---
    att_dots1_b<<<NN, 256, 0, stream>>>(h1b, as1, ad1, asrc, adst);
    agg1_f<<<NN, 256, 0, stream>>>(rowptr, esrc, asrc, adst, h1b, b1, o1b);

    // --- graph norm 1 + ELU (bf16 in place) ---
    fillk<<<4, 256, 0, stream>>>(msum, 0.f, 1024);
    colstat_b<<<(NN + 127) / 128, H1D, 0, stream>>>(o1b, msum, vsum, NN, 128);
    apply_norm_elu_b<<<(NN + 127) / 128, H1D, 0, stream>>>(o1b, msum, vsum, g1m, g1w, g1b, NN, 128);

    // --- GAT layer 2 ---
    gemm_mfma<1><<<dim3(1, MT), 256, 0, stream>>>(o1b, 512, 512, (const u16*)nullptr, 0, 0, w2T, h2b, 128, nullptr);
    att_dots2_b<<<NN, 128, 0, stream>>>(h2b, as2, ad2, asrc, adst);
    agg2_f<<<(NN + 3) / 4, 256, 0, stream>>>(rowptr, esrc, asrc, adst, h2b, b2, o2);

    // --- graph norm 2 + ELU + projection (fused) ---
    fillk<<<4, 256, 0, stream>>>(msum, 0.f, 1024);
    colstat<<<(NN + 127) / 128, HIDD, 0, stream>>>(o2, msum, vsum, NN, 128);
    norm2_proj<<<NN, 128, 0, stream>>>(o2, msum, vsum, g2m, g2w, g2b, Wn, bn, out);
}